// Round 1
// baseline (50185.876 us; speedup 1.0000x reference)
//
#include <hip/hip_runtime.h>
#include <hip/hip_cooperative_groups.h>

namespace cg = cooperative_groups;

#define BSZ 256
#define TSZ 256
#define SSZ 64
#define ASZ 16
#define HSZ 512

// ---------------------------------------------------------------------------
// Kernel 1: bu[b,t,i] = (tanh(u@Wb1+bb1) @ Wb2 + bb2).reshape(S,A) @ u
// written directly into d_out[b,t,i]. 16 samples per WG, 256 threads.
// ---------------------------------------------------------------------------
__global__ __launch_bounds__(256) void bu_kernel(
    const float* __restrict__ us,
    const float* __restrict__ Wb1, const float* __restrict__ bb1,
    const float* __restrict__ Wb2, const float* __restrict__ bb2,
    float* __restrict__ out)
{
    __shared__ float u_lds[16][16];
    __shared__ float hb_lds[16][HSZ + 4];

    const int tid = threadIdx.x;
    const long s0 = (long)blockIdx.x * 16;   // first flat sample (b*T + t)

    // load u tile: 16 samples x 16 actions
    u_lds[tid >> 4][tid & 15] = us[s0 * ASZ + tid];
    __syncthreads();

    // hb = tanh(u @ Wb1 + bb1): 16 x 512, 2 h per thread
    #pragma unroll
    for (int rep = 0; rep < 2; ++rep) {
        const int h = tid + rep * 256;
        float acc[16];
        const float b1 = bb1[h];
        #pragma unroll
        for (int s = 0; s < 16; ++s) acc[s] = b1;
        #pragma unroll
        for (int a = 0; a < ASZ; ++a) {
            const float w = Wb1[a * HSZ + h];
            #pragma unroll
            for (int s = 0; s < 16; ++s) acc[s] += u_lds[s][a] * w;
        }
        #pragma unroll
        for (int s = 0; s < 16; ++s) hb_lds[s][h] = tanhf(acc[s]);
    }
    __syncthreads();

    // bu[s,i] = sum_h hb[s,h] * (sum_a Wb2[h, i*16+a] * u[s,a]) + sum_a bb2[i*16+a]*u[s,a]
    const int i  = tid & 63;   // output state index
    const int sg = tid >> 6;   // sample group (4 samples each)

    float ur[4][ASZ];
    #pragma unroll
    for (int s4 = 0; s4 < 4; ++s4)
        #pragma unroll
        for (int a = 0; a < ASZ; ++a) ur[s4][a] = u_lds[sg * 4 + s4][a];

    float acc[4];
    {
        float wb[ASZ];
        const float4* bp = (const float4*)(bb2 + i * ASZ);
        #pragma unroll
        for (int q = 0; q < 4; ++q) {
            float4 v = bp[q];
            wb[q*4+0] = v.x; wb[q*4+1] = v.y; wb[q*4+2] = v.z; wb[q*4+3] = v.w;
        }
        #pragma unroll
        for (int s4 = 0; s4 < 4; ++s4) {
            float t = 0.f;
            #pragma unroll
            for (int a = 0; a < ASZ; ++a) t += wb[a] * ur[s4][a];
            acc[s4] = t;
        }
    }

    for (int h = 0; h < HSZ; ++h) {
        float w[ASZ];
        const float4* wp = (const float4*)(Wb2 + (size_t)h * (SSZ * ASZ) + i * ASZ);
        #pragma unroll
        for (int q = 0; q < 4; ++q) {
            float4 v = wp[q];
            w[q*4+0] = v.x; w[q*4+1] = v.y; w[q*4+2] = v.z; w[q*4+3] = v.w;
        }
        #pragma unroll
        for (int s4 = 0; s4 < 4; ++s4) {
            float t = 0.f;
            #pragma unroll
            for (int a = 0; a < ASZ; ++a) t += w[a] * ur[s4][a];
            acc[s4] += hb_lds[sg * 4 + s4][h] * t;
        }
    }

    #pragma unroll
    for (int s4 = 0; s4 < 4; ++s4)
        out[(s0 + sg * 4 + s4) * SSZ + i] = acc[s4];
}

// ---------------------------------------------------------------------------
// Kernel 2: sequential rollout. Persistent cooperative kernel.
// 256 WGs = 16 batch-tiles (16 batches each) x 16 col-tiles (256 Wa2 cols
// = 4 A-rows each). One grid.sync() per timestep.
// d_out[b,t,:] holds bu before step t, x_{t+1} after.
// ---------------------------------------------------------------------------
__global__ __launch_bounds__(256) void ssm_kernel(
    const float* __restrict__ x0,
    const float* __restrict__ Wa1, const float* __restrict__ ba1,
    const float* __restrict__ Wa2, const float* __restrict__ ba2,
    float* __restrict__ out)
{
    cg::grid_group grid = cg::this_grid();

    __shared__ float x_lds[16][SSZ];
    __shared__ float ha_lds[16][HSZ + 4];

    const int tid = threadIdx.x;
    const int bt = blockIdx.x >> 4;   // batch tile 0..15
    const int ct = blockIdx.x & 15;   // col tile  0..15
    const long bbase = (long)bt * 16; // first batch of tile

    for (int t = 0; t < TSZ; ++t) {
        // ---- load x_t for our 16 batches (float4 per thread) ----
        {
            const int s = tid >> 4, j4 = (tid & 15) * 4;
            const float* src = (t == 0)
                ? (x0 + (bbase + s) * SSZ + j4)
                : (out + ((bbase + s) * TSZ + (t - 1)) * SSZ + j4);
            *(float4*)&x_lds[s][j4] = *(const float4*)src;
        }
        __syncthreads();

        // ---- ha = tanh(x @ Wa1 + ba1): 16 x 512, 2 h per thread ----
        #pragma unroll
        for (int rep = 0; rep < 2; ++rep) {
            const int h = tid + rep * 256;
            float acc[16];
            const float b1 = ba1[h];
            #pragma unroll
            for (int s = 0; s < 16; ++s) acc[s] = b1;
            for (int j = 0; j < SSZ; ++j) {
                const float w = Wa1[j * HSZ + h];
                #pragma unroll
                for (int s = 0; s < 16; ++s) acc[s] += x_lds[s][j] * w;
            }
            #pragma unroll
            for (int s = 0; s < 16; ++s) ha_lds[s][h] = tanhf(acc[s]);
        }
        __syncthreads();

        // ---- G-slice + contraction: thread = (s, i, jb) ----
        const int s  = tid >> 4;        // sample in tile 0..15
        const int i  = (tid >> 2) & 3;  // local A-row 0..3
        const int jb = tid & 3;         // j-block of 16
        const int ig = ct * 4 + i;      // global A-row
        const int c0 = ig * SSZ + jb * 16; // global Wa2 col base

        float g[16];
        {
            const float4* bp = (const float4*)(ba2 + c0);
            #pragma unroll
            for (int q = 0; q < 4; ++q) {
                float4 v = bp[q];
                g[q*4+0] = v.x; g[q*4+1] = v.y; g[q*4+2] = v.z; g[q*4+3] = v.w;
            }
        }
        for (int h = 0; h < HSZ; ++h) {
            const float a = ha_lds[s][h];
            const float4* wp = (const float4*)(Wa2 + (size_t)h * (SSZ * SSZ) + c0);
            #pragma unroll
            for (int q = 0; q < 4; ++q) {
                float4 v = wp[q];
                g[q*4+0] += a * v.x; g[q*4+1] += a * v.y;
                g[q*4+2] += a * v.z; g[q*4+3] += a * v.w;
            }
        }

        float part = 0.f;
        #pragma unroll
        for (int jj = 0; jj < 16; ++jj) part += g[jj] * x_lds[s][jb * 16 + jj];
        part += __shfl_xor(part, 1);
        part += __shfl_xor(part, 2);

        if (jb == 0) {
            const long oidx = ((bbase + s) * TSZ + t) * SSZ + ig;
            out[oidx] = part + out[oidx];  // += bu (written by bu_kernel)
        }

        __threadfence();
        grid.sync();
    }
}

// ---------------------------------------------------------------------------
extern "C" void kernel_launch(void* const* d_in, const int* in_sizes, int n_in,
                              void* d_out, int out_size, void* d_ws, size_t ws_size,
                              hipStream_t stream) {
    const float* x0  = (const float*)d_in[0];
    const float* us  = (const float*)d_in[1];
    const float* Wa1 = (const float*)d_in[2];
    const float* ba1 = (const float*)d_in[3];
    const float* Wa2 = (const float*)d_in[4];
    const float* ba2 = (const float*)d_in[5];
    const float* Wb1 = (const float*)d_in[6];
    const float* bb1 = (const float*)d_in[7];
    const float* Wb2 = (const float*)d_in[8];
    const float* bb2 = (const float*)d_in[9];
    float* out = (float*)d_out;

    // Phase 1: precompute bu into d_out (B*T/16 = 4096 WGs)
    hipLaunchKernelGGL(bu_kernel, dim3((BSZ * TSZ) / 16), dim3(256), 0, stream,
                       us, Wb1, bb1, Wb2, bb2, out);

    // Phase 2: sequential rollout (cooperative, 256 WGs)
    void* args[] = {(void*)&x0, (void*)&Wa1, (void*)&ba1,
                    (void*)&Wa2, (void*)&ba2, (void*)&out};
    hipLaunchCooperativeKernel((const void*)ssm_kernel, dim3(256), dim3(256),
                               args, 0, stream);
}

// Round 2
// 26817.667 us; speedup vs baseline: 1.8714x; 1.8714x over previous
//
#include <hip/hip_runtime.h>
#include <hip/hip_cooperative_groups.h>

namespace cg = cooperative_groups;

#define BSZ 256
#define TSZ 256
#define SSZ 64
#define ASZ 16
#define HSZ 512

#define CCH 32                    // h-rows per staged chunk
#define NCH (HSZ / CCH)           // 16 chunks per step
#define HA_STR 20                 // padded [h][s] stride (floats), 16B-aligned

#define X_OFF   0                                  // [16][64]   = 1024 floats
#define HA_OFF  1024                               // [512][20]  = 10240 floats
#define W_OFF   (HA_OFF + HSZ * HA_STR)            // [3][32][256] = 24576 floats
#define SMEM_FLOATS (W_OFF + 3 * CCH * 256)        // 35840
#define SMEM_BYTES  (SMEM_FLOATS * 4)              // 143360 B

__device__ __forceinline__ void stage16(const float* gp, float* lp) {
    // async global->LDS, 16B/lane; LDS dest = wave-uniform base + lane*16
    __builtin_amdgcn_global_load_lds(
        (const __attribute__((address_space(1))) void*)gp,
        (__attribute__((address_space(3))) void*)lp, 16, 0, 0);
}

// ---------------------------------------------------------------------------
// Kernel 1: bu[b,t,i] = (tanh(u@Wb1+bb1) @ Wb2 + bb2).reshape(S,A) @ u
// written directly into d_out[b,t,i]. 16 samples per WG, 256 threads.
// (unchanged from round 1 — not the bottleneck this round)
// ---------------------------------------------------------------------------
__global__ __launch_bounds__(256) void bu_kernel(
    const float* __restrict__ us,
    const float* __restrict__ Wb1, const float* __restrict__ bb1,
    const float* __restrict__ Wb2, const float* __restrict__ bb2,
    float* __restrict__ out)
{
    __shared__ float u_lds[16][16];
    __shared__ float hb_lds[16][HSZ + 4];

    const int tid = threadIdx.x;
    const long s0 = (long)blockIdx.x * 16;

    u_lds[tid >> 4][tid & 15] = us[s0 * ASZ + tid];
    __syncthreads();

    #pragma unroll
    for (int rep = 0; rep < 2; ++rep) {
        const int h = tid + rep * 256;
        float acc[16];
        const float b1 = bb1[h];
        #pragma unroll
        for (int s = 0; s < 16; ++s) acc[s] = b1;
        #pragma unroll
        for (int a = 0; a < ASZ; ++a) {
            const float w = Wb1[a * HSZ + h];
            #pragma unroll
            for (int s = 0; s < 16; ++s) acc[s] += u_lds[s][a] * w;
        }
        #pragma unroll
        for (int s = 0; s < 16; ++s) hb_lds[s][h] = tanhf(acc[s]);
    }
    __syncthreads();

    const int i  = tid & 63;
    const int sg = tid >> 6;

    float ur[4][ASZ];
    #pragma unroll
    for (int s4 = 0; s4 < 4; ++s4)
        #pragma unroll
        for (int a = 0; a < ASZ; ++a) ur[s4][a] = u_lds[sg * 4 + s4][a];

    float acc[4];
    {
        float wb[ASZ];
        const float4* bp = (const float4*)(bb2 + i * ASZ);
        #pragma unroll
        for (int q = 0; q < 4; ++q) {
            float4 v = bp[q];
            wb[q*4+0] = v.x; wb[q*4+1] = v.y; wb[q*4+2] = v.z; wb[q*4+3] = v.w;
        }
        #pragma unroll
        for (int s4 = 0; s4 < 4; ++s4) {
            float t = 0.f;
            #pragma unroll
            for (int a = 0; a < ASZ; ++a) t += wb[a] * ur[s4][a];
            acc[s4] = t;
        }
    }

    for (int h = 0; h < HSZ; ++h) {
        float w[ASZ];
        const float4* wp = (const float4*)(Wb2 + (size_t)h * (SSZ * ASZ) + i * ASZ);
        #pragma unroll
        for (int q = 0; q < 4; ++q) {
            float4 v = wp[q];
            w[q*4+0] = v.x; w[q*4+1] = v.y; w[q*4+2] = v.z; w[q*4+3] = v.w;
        }
        #pragma unroll
        for (int s4 = 0; s4 < 4; ++s4) {
            float t = 0.f;
            #pragma unroll
            for (int a = 0; a < ASZ; ++a) t += w[a] * ur[s4][a];
            acc[s4] += hb_lds[sg * 4 + s4][h] * t;
        }
    }

    #pragma unroll
    for (int s4 = 0; s4 < 4; ++s4)
        out[(s0 + sg * 4 + s4) * SSZ + i] = acc[s4];
}

// ---------------------------------------------------------------------------
// Kernel 2: sequential rollout, async-staged Wa2 through LDS.
// 256 WGs = 16 batch-tiles x 16 col-tiles. 1 WG/CU (140KB LDS).
// Per step: stage chunk0 under ha phase; 16-chunk pipelined G-GEMM with
// counted vmcnt(8) + raw s_barrier (1 barrier/chunk, 3 rotating buffers).
// Thread tile: 4 samples (wave=sg) x 4 cols -> ha read is LDS broadcast,
// w read is contiguous conflict-free ds_read_b128.
// ---------------------------------------------------------------------------
__global__ __launch_bounds__(256, 1) void ssm_kernel(
    const float* __restrict__ x0,
    const float* __restrict__ Wa1, const float* __restrict__ ba1,
    const float* __restrict__ Wa2, const float* __restrict__ ba2,
    float* __restrict__ out)
{
    cg::grid_group grid = cg::this_grid();
    extern __shared__ float smem[];
    float* x_lds = smem + X_OFF;     // [16][64]
    float* ha_t  = smem + HA_OFF;    // [512][HA_STR]
    float* wch   = smem + W_OFF;     // [3][CCH][256]

    const int tid  = threadIdx.x;
    const int lane = tid & 63;
    const int wv   = tid >> 6;
    const int bt = blockIdx.x >> 4;
    const int ct = blockIdx.x & 15;
    const long bbase = (long)bt * 16;

    const int cg = lane;             // column group 0..63 (4 cols each)
    const int sg = wv;               // sample group = wave (4 samples each)
    const int c0 = ct * 256 + cg * 4;
    const float4 ba2r = *(const float4*)(ba2 + c0);
    const int il = cg >> 4;          // local A-row 0..3
    const int ig = ct * 4 + il;      // global A-row
    const int j0 = (cg & 15) * 4;    // x sub-block for epilogue

    for (int t = 0; t < TSZ; ++t) {
        // ---- stage chunk 0 (latency hidden under x-load + ha phase) ----
        #pragma unroll
        for (int it = 0; it < 8; ++it) {
            stage16(Wa2 + (size_t)(wv * 8 + it) * (SSZ * SSZ) + ct * 256 + lane * 4,
                    wch + (0 * CCH + wv * 8 + it) * 256);
        }

        // ---- load x tile ----
        {
            const int s = tid >> 4, j4 = (tid & 15) * 4;
            const float* src = (t == 0)
                ? (x0 + (bbase + s) * SSZ + j4)
                : (out + ((bbase + s) * TSZ + (t - 1)) * SSZ + j4);
            *(float4*)&x_lds[s * SSZ + j4] = *(const float4*)src;
        }

        // ---- prefetch bu (consumed in epilogue; hides RMW load latency) ----
        float bu_r[4];
        #pragma unroll
        for (int si = 0; si < 4; ++si)
            bu_r[si] = out[((bbase + sg * 4 + si) * TSZ + t) * SSZ + ig];

        asm volatile("s_waitcnt lgkmcnt(0)" ::: "memory");
        __builtin_amdgcn_s_barrier();
        __builtin_amdgcn_sched_barrier(0);

        // ---- ha = tanh(x @ Wa1 + ba1), transposed [h][s] ----
        #pragma unroll
        for (int rep = 0; rep < 2; ++rep) {
            const int h = tid + rep * 256;
            float acc[16];
            const float b1 = ba1[h];
            #pragma unroll
            for (int s = 0; s < 16; ++s) acc[s] = b1;
            #pragma unroll 4
            for (int jb = 0; jb < 16; ++jb) {
                const float w0 = Wa1[(jb * 4 + 0) * HSZ + h];
                const float w1 = Wa1[(jb * 4 + 1) * HSZ + h];
                const float w2 = Wa1[(jb * 4 + 2) * HSZ + h];
                const float w3 = Wa1[(jb * 4 + 3) * HSZ + h];
                #pragma unroll
                for (int s = 0; s < 16; ++s) {
                    const float4 xr = *(const float4*)&x_lds[s * SSZ + jb * 4];
                    acc[s] += xr.x * w0 + xr.y * w1 + xr.z * w2 + xr.w * w3;
                }
            }
            #pragma unroll
            for (int s = 0; s < 16; ++s) acc[s] = tanhf(acc[s]);
            #pragma unroll
            for (int q = 0; q < 4; ++q)
                *(float4*)&ha_t[h * HA_STR + q * 4] =
                    make_float4(acc[q*4+0], acc[q*4+1], acc[q*4+2], acc[q*4+3]);
        }
        asm volatile("s_waitcnt lgkmcnt(0)" ::: "memory");
        __builtin_amdgcn_s_barrier();
        __builtin_amdgcn_sched_barrier(0);

        // ---- pipelined G-GEMM: G = ha @ Wa2-slice (+ba2), fused x-contract ----
        float4 g0 = ba2r, g1 = ba2r, g2 = ba2r, g3 = ba2r;
        int bcur = 0, bnext = 1;
        for (int k = 0; k < NCH; ++k) {
            if (k + 1 < NCH) {
                #pragma unroll
                for (int it = 0; it < 8; ++it) {
                    stage16(Wa2 + (size_t)((k + 1) * CCH + wv * 8 + it) * (SSZ * SSZ)
                                + ct * 256 + lane * 4,
                            wch + (bnext * CCH + wv * 8 + it) * 256);
                }
                asm volatile("s_waitcnt vmcnt(8)" ::: "memory");
            } else {
                asm volatile("s_waitcnt vmcnt(0)" ::: "memory");
            }
            __builtin_amdgcn_s_barrier();
            __builtin_amdgcn_sched_barrier(0);

            const float* wb = wch + bcur * (CCH * 256);
            const float* hb = ha_t + (k * CCH) * HA_STR;
            #pragma unroll 8
            for (int hl = 0; hl < CCH; ++hl) {
                const float4 w4 = *(const float4*)(wb + hl * 256 + cg * 4);
                const float4 a4 = *(const float4*)(hb + hl * HA_STR + sg * 4);
                g0.x += a4.x * w4.x; g0.y += a4.x * w4.y; g0.z += a4.x * w4.z; g0.w += a4.x * w4.w;
                g1.x += a4.y * w4.x; g1.y += a4.y * w4.y; g1.z += a4.y * w4.z; g1.w += a4.y * w4.w;
                g2.x += a4.z * w4.x; g2.y += a4.z * w4.y; g2.z += a4.z * w4.z; g2.w += a4.z * w4.w;
                g3.x += a4.w * w4.x; g3.y += a4.w * w4.y; g3.z += a4.w * w4.z; g3.w += a4.w * w4.w;
            }
            bcur = bnext;
            bnext = (bnext + 1 == 3) ? 0 : bnext + 1;
        }

        // ---- epilogue: part = g . x, reduce over 16 lanes, += bu ----
        float part[4];
        #pragma unroll
        for (int si = 0; si < 4; ++si) {
            const float4 xr = *(const float4*)&x_lds[(sg * 4 + si) * SSZ + j0];
            const float4 gv = (si == 0) ? g0 : (si == 1) ? g1 : (si == 2) ? g2 : g3;
            part[si] = gv.x * xr.x + gv.y * xr.y + gv.z * xr.z + gv.w * xr.w;
        }
        #pragma unroll
        for (int si = 0; si < 4; ++si) {
            part[si] += __shfl_xor(part[si], 1);
            part[si] += __shfl_xor(part[si], 2);
            part[si] += __shfl_xor(part[si], 4);
            part[si] += __shfl_xor(part[si], 8);
        }
        if ((cg & 15) == 0) {
            #pragma unroll
            for (int si = 0; si < 4; ++si) {
                const long oidx = ((bbase + sg * 4 + si) * TSZ + t) * SSZ + ig;
                out[oidx] = part[si] + bu_r[si];
            }
        }

        __threadfence();
        grid.sync();
    }
}

// ---------------------------------------------------------------------------
extern "C" void kernel_launch(void* const* d_in, const int* in_sizes, int n_in,
                              void* d_out, int out_size, void* d_ws, size_t ws_size,
                              hipStream_t stream) {
    const float* x0  = (const float*)d_in[0];
    const float* us  = (const float*)d_in[1];
    const float* Wa1 = (const float*)d_in[2];
    const float* ba1 = (const float*)d_in[3];
    const float* Wa2 = (const float*)d_in[4];
    const float* ba2 = (const float*)d_in[5];
    const float* Wb1 = (const float*)d_in[6];
    const float* bb1 = (const float*)d_in[7];
    const float* Wb2 = (const float*)d_in[8];
    const float* bb2 = (const float*)d_in[9];
    float* out = (float*)d_out;

    // Phase 1: bu -> d_out (B*T/16 = 4096 WGs)
    hipLaunchKernelGGL(bu_kernel, dim3((BSZ * TSZ) / 16), dim3(256), 0, stream,
                       us, Wb1, bb1, Wb2, bb2, out);

    // Phase 2: sequential rollout (cooperative, 256 WGs, 140KB dynamic LDS)
    (void)hipFuncSetAttribute((const void*)ssm_kernel,
                              hipFuncAttributeMaxDynamicSharedMemorySize, SMEM_BYTES);
    void* args[] = {(void*)&x0, (void*)&Wa1, (void*)&ba1,
                    (void*)&Wa2, (void*)&ba2, (void*)&out};
    hipLaunchCooperativeKernel((const void*)ssm_kernel, dim3(256), dim3(256),
                               args, SMEM_BYTES, stream);
}

// Round 3
// 19194.789 us; speedup vs baseline: 2.6146x; 1.3971x over previous
//
#include <hip/hip_runtime.h>
#include <hip/hip_cooperative_groups.h>

#define BSZ 256
#define TSZ 256
#define SSZ 64
#define ASZ 16
#define HSZ 512

#define CCH 32                    // h-rows per staged chunk
#define NCH (HSZ / CCH)           // 16 chunks per step
#define HA_STR 20                 // padded [h][s] stride (floats), 16B-aligned

#define X_OFF   0                                  // [16][64]   = 1024 floats
#define HA_OFF  1024                               // [512][20]  = 10240 floats
#define W_OFF   (HA_OFF + HSZ * HA_STR)            // [3][32][256] = 24576 floats
#define SMEM_FLOATS (W_OFF + 3 * CCH * 256)        // 35840
#define SMEM_BYTES  (SMEM_FLOATS * 4)              // 143360 B

__device__ __forceinline__ void stage16(const float* gp, float* lp) {
    // async global->LDS, 16B/lane; LDS dest = wave-uniform base + lane*16
    __builtin_amdgcn_global_load_lds(
        (const __attribute__((address_space(1))) void*)gp,
        (__attribute__((address_space(3))) void*)lp, 16, 0, 0);
}

// ---------------------------------------------------------------------------
// Kernel 1: bu[b,t,i] = (tanh(u@Wb1+bb1) @ Wb2 + bb2).reshape(S,A) @ u
// written directly into d_out[b,t,i]. 16 samples per WG, 256 threads.
// ---------------------------------------------------------------------------
__global__ __launch_bounds__(256) void bu_kernel(
    const float* __restrict__ us,
    const float* __restrict__ Wb1, const float* __restrict__ bb1,
    const float* __restrict__ Wb2, const float* __restrict__ bb2,
    float* __restrict__ out)
{
    __shared__ float u_lds[16][16];
    __shared__ float hb_lds[16][HSZ + 4];

    const int tid = threadIdx.x;
    const long s0 = (long)blockIdx.x * 16;

    u_lds[tid >> 4][tid & 15] = us[s0 * ASZ + tid];
    __syncthreads();

    #pragma unroll
    for (int rep = 0; rep < 2; ++rep) {
        const int h = tid + rep * 256;
        float acc[16];
        const float b1 = bb1[h];
        #pragma unroll
        for (int s = 0; s < 16; ++s) acc[s] = b1;
        #pragma unroll
        for (int a = 0; a < ASZ; ++a) {
            const float w = Wb1[a * HSZ + h];
            #pragma unroll
            for (int s = 0; s < 16; ++s) acc[s] += u_lds[s][a] * w;
        }
        #pragma unroll
        for (int s = 0; s < 16; ++s) hb_lds[s][h] = tanhf(acc[s]);
    }
    __syncthreads();

    const int i  = tid & 63;
    const int sg = tid >> 6;

    float ur[4][ASZ];
    #pragma unroll
    for (int s4 = 0; s4 < 4; ++s4)
        #pragma unroll
        for (int a = 0; a < ASZ; ++a) ur[s4][a] = u_lds[sg * 4 + s4][a];

    float acc[4];
    {
        float wb[ASZ];
        const float4* bp = (const float4*)(bb2 + i * ASZ);
        #pragma unroll
        for (int q = 0; q < 4; ++q) {
            float4 v = bp[q];
            wb[q*4+0] = v.x; wb[q*4+1] = v.y; wb[q*4+2] = v.z; wb[q*4+3] = v.w;
        }
        #pragma unroll
        for (int s4 = 0; s4 < 4; ++s4) {
            float t = 0.f;
            #pragma unroll
            for (int a = 0; a < ASZ; ++a) t += wb[a] * ur[s4][a];
            acc[s4] = t;
        }
    }

    for (int h = 0; h < HSZ; ++h) {
        float w[ASZ];
        const float4* wp = (const float4*)(Wb2 + (size_t)h * (SSZ * ASZ) + i * ASZ);
        #pragma unroll
        for (int q = 0; q < 4; ++q) {
            float4 v = wp[q];
            w[q*4+0] = v.x; w[q*4+1] = v.y; w[q*4+2] = v.z; w[q*4+3] = v.w;
        }
        #pragma unroll
        for (int s4 = 0; s4 < 4; ++s4) {
            float t = 0.f;
            #pragma unroll
            for (int a = 0; a < ASZ; ++a) t += w[a] * ur[s4][a];
            acc[s4] += hb_lds[sg * 4 + s4][h] * t;
        }
    }

    #pragma unroll
    for (int s4 = 0; s4 < 4; ++s4)
        out[(s0 + sg * 4 + s4) * SSZ + i] = acc[s4];
}

// ---------------------------------------------------------------------------
// Kernel 2: sequential rollout. Cooperative launch ONLY for co-residency.
// Sync: per-bt-group 16-WG barrier through step-indexed L3 counters.
//   writer: per-wave agent release fence -> syncthreads -> 1 atomicAdd
//   reader: thread0 relaxed spin -> syncthreads -> agent acquire fence
// Staging: Wa2 column slice, 16 chunks, 2-deep global_load_lds pipeline,
// counted vmcnt (never 0 mid-loop).
// ---------------------------------------------------------------------------
__global__ __launch_bounds__(256, 1) void ssm_kernel(
    const float* __restrict__ x0,
    const float* __restrict__ Wa1, const float* __restrict__ ba1,
    const float* __restrict__ Wa2, const float* __restrict__ ba2,
    float* __restrict__ out, unsigned* __restrict__ cnt)
{
    extern __shared__ float smem[];
    float* x_lds = smem + X_OFF;     // [16][64]
    float* ha_t  = smem + HA_OFF;    // [512][HA_STR]
    float* wch   = smem + W_OFF;     // [3][CCH][256]

    const int tid  = threadIdx.x;
    const int lane = tid & 63;
    const int wv   = tid >> 6;
    const int bt = blockIdx.x >> 4;   // batch tile 0..15  (sync group)
    const int ct = blockIdx.x & 15;   // col tile 0..15 (ct%8 = XCD -> Wa2 slice L2 locality)
    const long bbase = (long)bt * 16;

    const int cgi = lane;             // column group 0..63 (4 cols each)
    const int sg  = wv;               // sample group = wave (4 samples each)
    const int c0 = ct * 256 + cgi * 4;
    const float4 ba2r = *(const float4*)(ba2 + c0);
    const int il = cgi >> 4;          // local A-row 0..3
    const int ig = ct * 4 + il;       // global A-row
    const int j0 = (cgi & 15) * 4;    // x sub-block for epilogue

    unsigned* mycnt = cnt + bt * TSZ;

    for (int t = 0; t < TSZ; ++t) {
        // ---- wait for x_{t-1} from our 16-WG group ----
        if (t > 0) {
            if (tid == 0) {
                while (__hip_atomic_load(&mycnt[t - 1], __ATOMIC_RELAXED,
                                         __HIP_MEMORY_SCOPE_AGENT) < 16u) {}
            }
            __syncthreads();
            __builtin_amdgcn_fence(__ATOMIC_ACQUIRE, "agent");
        }

        // ---- stage chunk 0 (hidden under x-load + ha phase) ----
        #pragma unroll
        for (int it = 0; it < 8; ++it) {
            stage16(Wa2 + (size_t)(wv * 8 + it) * (SSZ * SSZ) + ct * 256 + lane * 4,
                    wch + (0 * CCH + wv * 8 + it) * 256);
        }

        // ---- load x tile ----
        {
            const int s = tid >> 4, j4 = (tid & 15) * 4;
            const float* src = (t == 0)
                ? (x0 + (bbase + s) * SSZ + j4)
                : (out + ((bbase + s) * TSZ + (t - 1)) * SSZ + j4);
            *(float4*)&x_lds[s * SSZ + j4] = *(const float4*)src;
        }

        // ---- prefetch bu (consumed in epilogue) ----
        float bu_r[4];
        #pragma unroll
        for (int si = 0; si < 4; ++si)
            bu_r[si] = out[((bbase + sg * 4 + si) * TSZ + t) * SSZ + ig];

        asm volatile("s_waitcnt lgkmcnt(0)" ::: "memory");
        __builtin_amdgcn_s_barrier();
        __builtin_amdgcn_sched_barrier(0);

        // ---- ha = tanh(x @ Wa1 + ba1), transposed [h][s] ----
        #pragma unroll
        for (int rep = 0; rep < 2; ++rep) {
            const int h = tid + rep * 256;
            float acc[16];
            const float b1 = ba1[h];
            #pragma unroll
            for (int s = 0; s < 16; ++s) acc[s] = b1;
            #pragma unroll 4
            for (int jb = 0; jb < 16; ++jb) {
                const float w0 = Wa1[(jb * 4 + 0) * HSZ + h];
                const float w1 = Wa1[(jb * 4 + 1) * HSZ + h];
                const float w2 = Wa1[(jb * 4 + 2) * HSZ + h];
                const float w3 = Wa1[(jb * 4 + 3) * HSZ + h];
                #pragma unroll
                for (int s = 0; s < 16; ++s) {
                    const float4 xr = *(const float4*)&x_lds[s * SSZ + jb * 4];
                    acc[s] += xr.x * w0 + xr.y * w1 + xr.z * w2 + xr.w * w3;
                }
            }
            #pragma unroll
            for (int s = 0; s < 16; ++s) acc[s] = tanhf(acc[s]);
            #pragma unroll
            for (int q = 0; q < 4; ++q)
                *(float4*)&ha_t[h * HA_STR + q * 4] =
                    make_float4(acc[q*4+0], acc[q*4+1], acc[q*4+2], acc[q*4+3]);
        }
        // ---- stage chunk 1 before first wait (2-deep pipeline) ----
        #pragma unroll
        for (int it = 0; it < 8; ++it) {
            stage16(Wa2 + (size_t)(CCH + wv * 8 + it) * (SSZ * SSZ) + ct * 256 + lane * 4,
                    wch + (1 * CCH + wv * 8 + it) * 256);
        }
        asm volatile("s_waitcnt lgkmcnt(0)" ::: "memory");
        __builtin_amdgcn_s_barrier();
        __builtin_amdgcn_sched_barrier(0);

        // ---- pipelined G-GEMM: G = ha @ Wa2-slice (+ba2), fused x-contract ----
        float4 g0 = ba2r, g1 = ba2r, g2 = ba2r, g3 = ba2r;
        for (int k = 0; k < NCH; ++k) {
            if (k + 2 < NCH) {
                #pragma unroll
                for (int it = 0; it < 8; ++it) {
                    stage16(Wa2 + (size_t)((k + 2) * CCH + wv * 8 + it) * (SSZ * SSZ)
                                + ct * 256 + lane * 4,
                            wch + (((k + 2) % 3) * CCH + wv * 8 + it) * 256);
                }
                asm volatile("s_waitcnt vmcnt(16)" ::: "memory"); // chunk k landed
            } else if (k + 1 < NCH) {
                asm volatile("s_waitcnt vmcnt(8)" ::: "memory");  // chunk k landed
            } else {
                asm volatile("s_waitcnt vmcnt(0)" ::: "memory");  // chunk 15 landed
            }
            __builtin_amdgcn_s_barrier();
            __builtin_amdgcn_sched_barrier(0);

            const float* wb = wch + (k % 3) * (CCH * 256);
            const float* hb = ha_t + (k * CCH) * HA_STR;
            #pragma unroll 8
            for (int hl = 0; hl < CCH; ++hl) {
                const float4 w4 = *(const float4*)(wb + hl * 256 + cgi * 4);
                const float4 a4 = *(const float4*)(hb + hl * HA_STR + sg * 4);
                g0.x += a4.x * w4.x; g0.y += a4.x * w4.y; g0.z += a4.x * w4.z; g0.w += a4.x * w4.w;
                g1.x += a4.y * w4.x; g1.y += a4.y * w4.y; g1.z += a4.y * w4.z; g1.w += a4.y * w4.w;
                g2.x += a4.z * w4.x; g2.y += a4.z * w4.y; g2.z += a4.z * w4.z; g2.w += a4.z * w4.w;
                g3.x += a4.w * w4.x; g3.y += a4.w * w4.y; g3.z += a4.w * w4.z; g3.w += a4.w * w4.w;
            }
        }

        // ---- epilogue: part = g . x, reduce over 16 lanes, += bu ----
        float part[4];
        #pragma unroll
        for (int si = 0; si < 4; ++si) {
            const float4 xr = *(const float4*)&x_lds[(sg * 4 + si) * SSZ + j0];
            const float4 gv = (si == 0) ? g0 : (si == 1) ? g1 : (si == 2) ? g2 : g3;
            part[si] = gv.x * xr.x + gv.y * xr.y + gv.z * xr.z + gv.w * xr.w;
        }
        #pragma unroll
        for (int si = 0; si < 4; ++si) {
            part[si] += __shfl_xor(part[si], 1);
            part[si] += __shfl_xor(part[si], 2);
            part[si] += __shfl_xor(part[si], 4);
            part[si] += __shfl_xor(part[si], 8);
        }
        if ((cgi & 15) == 0) {
            #pragma unroll
            for (int si = 0; si < 4; ++si) {
                const long oidx = ((bbase + sg * 4 + si) * TSZ + t) * SSZ + ig;
                out[oidx] = part[si] + bu_r[si];
            }
        }

        // ---- release + arrive (per-wave writeback, one atomic per WG) ----
        __builtin_amdgcn_fence(__ATOMIC_RELEASE, "agent");
        __syncthreads();
        if (tid == 0)
            __hip_atomic_fetch_add(&mycnt[t], 1u, __ATOMIC_RELAXED,
                                   __HIP_MEMORY_SCOPE_AGENT);
    }
}

// ---------------------------------------------------------------------------
extern "C" void kernel_launch(void* const* d_in, const int* in_sizes, int n_in,
                              void* d_out, int out_size, void* d_ws, size_t ws_size,
                              hipStream_t stream) {
    const float* x0  = (const float*)d_in[0];
    const float* us  = (const float*)d_in[1];
    const float* Wa1 = (const float*)d_in[2];
    const float* ba1 = (const float*)d_in[3];
    const float* Wa2 = (const float*)d_in[4];
    const float* ba2 = (const float*)d_in[5];
    const float* Wb1 = (const float*)d_in[6];
    const float* bb1 = (const float*)d_in[7];
    const float* Wb2 = (const float*)d_in[8];
    const float* bb2 = (const float*)d_in[9];
    float* out = (float*)d_out;
    unsigned* cnt = (unsigned*)d_ws;   // [16][256] step-indexed arrival counters

    // zero the barrier counters (graph-capturable, stream-ordered)
    hipMemsetAsync(cnt, 0, 16 * TSZ * sizeof(unsigned), stream);

    // Phase 1: bu -> d_out (B*T/16 = 4096 WGs)
    hipLaunchKernelGGL(bu_kernel, dim3((BSZ * TSZ) / 16), dim3(256), 0, stream,
                       us, Wb1, bb1, Wb2, bb2, out);

    // Phase 2: sequential rollout (cooperative for co-residency; 140KB LDS)
    (void)hipFuncSetAttribute((const void*)ssm_kernel,
                              hipFuncAttributeMaxDynamicSharedMemorySize, SMEM_BYTES);
    void* args[] = {(void*)&x0, (void*)&Wa1, (void*)&ba1,
                    (void*)&Wa2, (void*)&ba2, (void*)&out, (void*)&cnt};
    hipLaunchCooperativeKernel((const void*)ssm_kernel, dim3(256), dim3(256),
                               args, SMEM_BYTES, stream);
}

// Round 6
// 9582.953 us; speedup vs baseline: 5.2370x; 2.0030x over previous
//
#include <hip/hip_runtime.h>

#define BSZ 256
#define TSZ 256
#define SSZ 64
#define ASZ 16
#define HSZ 512

#define NCH 16                    // 16 chunks of 32 h-rows per step
#define HA_STR 20                 // padded [h][s] stride (floats)

#define X_OFF   0                                  // [16][64]    = 1024 floats
#define HA_OFF  1024                               // [512][20]   = 10240 floats
#define W_OFF   (HA_OFF + HSZ * HA_STR)            // [3][32][256]= 24576 floats
#define RED_OFF (W_OFF + 3 * 32 * 256)             // [4][4][16]  = 256 floats
#define SMEM_FLOATS (RED_OFF + 256)                // 36096
#define SMEM_BYTES  (SMEM_FLOATS * 4)              // 144384 B

typedef float f32x4 __attribute__((ext_vector_type(4)));
typedef unsigned long long u64;

__device__ __forceinline__ void stage16(const float* gp, float* lp) {
    // async global->LDS, 16B/lane; LDS dest = wave-uniform base + lane*16
    __builtin_amdgcn_global_load_lds(
        (const __attribute__((address_space(1))) void*)gp,
        (__attribute__((address_space(3))) void*)lp, 16, 0, 0);
}

// Tagged-word exchange: value and validity in ONE 8B atomic object.
// No fences, no separate counters, no ordering assumptions.
__device__ __forceinline__ float wait_tag(const u64* p, unsigned tag) {
    u64 v = __hip_atomic_load(p, __ATOMIC_RELAXED, __HIP_MEMORY_SCOPE_AGENT);
    while ((unsigned)(v >> 32) != tag) {
        __builtin_amdgcn_s_sleep(1);
        v = __hip_atomic_load(p, __ATOMIC_RELAXED, __HIP_MEMORY_SCOPE_AGENT);
    }
    return __uint_as_float((unsigned)v);
}

// ---------------------------------------------------------------------------
// Kernel 1: bu[b,t,i] = (tanh(u@Wb1+bb1) @ Wb2 + bb2).reshape(S,A) @ u
// written directly into d_out[b,t,i]. 16 samples per WG. (unchanged)
// ---------------------------------------------------------------------------
__global__ __launch_bounds__(256) void bu_kernel(
    const float* __restrict__ us,
    const float* __restrict__ Wb1, const float* __restrict__ bb1,
    const float* __restrict__ Wb2, const float* __restrict__ bb2,
    float* __restrict__ out)
{
    __shared__ float u_lds[16][16];
    __shared__ float hb_lds[16][HSZ + 4];

    const int tid = threadIdx.x;
    const long s0 = (long)blockIdx.x * 16;

    u_lds[tid >> 4][tid & 15] = us[s0 * ASZ + tid];
    __syncthreads();

    #pragma unroll
    for (int rep = 0; rep < 2; ++rep) {
        const int h = tid + rep * 256;
        float acc[16];
        const float b1 = bb1[h];
        #pragma unroll
        for (int s = 0; s < 16; ++s) acc[s] = b1;
        #pragma unroll
        for (int a = 0; a < ASZ; ++a) {
            const float w = Wb1[a * HSZ + h];
            #pragma unroll
            for (int s = 0; s < 16; ++s) acc[s] += u_lds[s][a] * w;
        }
        #pragma unroll
        for (int s = 0; s < 16; ++s) hb_lds[s][h] = tanhf(acc[s]);
    }
    __syncthreads();

    const int i  = tid & 63;
    const int sg = tid >> 6;

    float ur[4][ASZ];
    #pragma unroll
    for (int s4 = 0; s4 < 4; ++s4)
        #pragma unroll
        for (int a = 0; a < ASZ; ++a) ur[s4][a] = u_lds[sg * 4 + s4][a];

    float acc[4];
    {
        float wb[ASZ];
        const float4* bp = (const float4*)(bb2 + i * ASZ);
        #pragma unroll
        for (int q = 0; q < 4; ++q) {
            float4 v = bp[q];
            wb[q*4+0] = v.x; wb[q*4+1] = v.y; wb[q*4+2] = v.z; wb[q*4+3] = v.w;
        }
        #pragma unroll
        for (int s4 = 0; s4 < 4; ++s4) {
            float t = 0.f;
            #pragma unroll
            for (int a = 0; a < ASZ; ++a) t += wb[a] * ur[s4][a];
            acc[s4] = t;
        }
    }

    for (int h = 0; h < HSZ; ++h) {
        float w[ASZ];
        const float4* wp = (const float4*)(Wb2 + (size_t)h * (SSZ * ASZ) + i * ASZ);
        #pragma unroll
        for (int q = 0; q < 4; ++q) {
            float4 v = wp[q];
            w[q*4+0] = v.x; w[q*4+1] = v.y; w[q*4+2] = v.z; w[q*4+3] = v.w;
        }
        #pragma unroll
        for (int s4 = 0; s4 < 4; ++s4) {
            float t = 0.f;
            #pragma unroll
            for (int a = 0; a < ASZ; ++a) t += w[a] * ur[s4][a];
            acc[s4] += hb_lds[sg * 4 + s4][h] * t;
        }
    }

    #pragma unroll
    for (int s4 = 0; s4 < 4; ++s4)
        out[(s0 + sg * 4 + s4) * SSZ + i] = acc[s4];
}

// ---------------------------------------------------------------------------
// Kernel 2: sequential rollout. 256 WGs = 16 bt-groups x 16 ct. 1 WG/CU.
// Exchange: xbuf64[4 slots][256 b][64 i] of (tag<<32|f32bits), relaxed
// agent-scope 8B atomics. Writer of step t stores tag t+1 into slot t&3;
// reader at step t spins for tag t in slot (t-1)&3. Single-object atomicity
// => no fences/ordering needed. Slots zeroed per launch (replay-safe).
// G-GEMM: h-split by wave (each wave consumes exactly the rows it staged ->
// NO barriers in the 16-chunk pipelined loop), thread tile 16 samples x 4
// cols, cross-wave partial reduction through LDS. (unchanged from round 5)
// ---------------------------------------------------------------------------
__global__ __launch_bounds__(256, 1) void ssm_kernel(
    const float* __restrict__ x0,
    const float* __restrict__ Wa1, const float* __restrict__ ba1,
    const float* __restrict__ Wa2, const float* __restrict__ ba2,
    float* __restrict__ out, u64* __restrict__ xbuf)
{
    extern __shared__ float smem[];
    float* x_lds = smem + X_OFF;     // [16][64]
    float* ha_t  = smem + HA_OFF;    // [512][HA_STR]
    float* wch   = smem + W_OFF;     // [3][32][256]
    float* red   = smem + RED_OFF;   // [4 wv][4 il][16 s]

    const int tid  = threadIdx.x;
    const int lane = tid & 63;
    const int wv   = tid >> 6;
    const int bt = blockIdx.x >> 4;
    const int ct = blockIdx.x & 15;
    const long bbase = (long)bt * 16;

    const int c0 = ct * 256 + lane * 4;          // 4 global Wa2 cols per thread
    const f32x4 ba2r = *(const f32x4*)(ba2 + c0);
    const int j0 = (lane & 15) * 4;              // x sub-block for contraction
    const int s_e = lane & 15, il_e = lane >> 4; // wave0 epilogue mapping

    for (int t = 0; t < TSZ; ++t) {
        // ---- obtain x_{t-1} FIRST (the inter-WG critical path) ----
        const int sx = tid >> 4, jx = (tid & 15) * 4;
        float xv0, xv1, xv2, xv3;
        if (t > 0) {
            const u64* xs = xbuf + (size_t)((t - 1) & 3) * (BSZ * SSZ)
                          + (bbase + sx) * SSZ + jx;
            xv0 = wait_tag(xs + 0, (unsigned)t);
            xv1 = wait_tag(xs + 1, (unsigned)t);
            xv2 = wait_tag(xs + 2, (unsigned)t);
            xv3 = wait_tag(xs + 3, (unsigned)t);
        } else {
            const f32x4 x4 = *(const f32x4*)(x0 + (bbase + sx) * SSZ + jx);
            xv0 = x4.x; xv1 = x4.y; xv2 = x4.z; xv3 = x4.w;
        }

        // ---- stage chunks 0,1 (this wave's own 8 rows of each) ----
        #pragma unroll
        for (int it = 0; it < 8; ++it)
            stage16(Wa2 + (size_t)(wv * 8 + it) * 4096 + c0,
                    wch + (0 * 32 + wv * 8 + it) * 256);
        #pragma unroll
        for (int it = 0; it < 8; ++it)
            stage16(Wa2 + (size_t)(32 + wv * 8 + it) * 4096 + c0,
                    wch + (1 * 32 + wv * 8 + it) * 256);

        // ---- bu (wave0 only; cached load of bytes only bu_kernel wrote) ----
        float bu_v = 0.f;
        if (wv == 0)
            bu_v = out[((bbase + s_e) * TSZ + t) * SSZ + (ct * 4 + il_e)];

        // ---- publish x to LDS ----
        x_lds[sx * SSZ + jx + 0] = xv0;
        x_lds[sx * SSZ + jx + 1] = xv1;
        x_lds[sx * SSZ + jx + 2] = xv2;
        x_lds[sx * SSZ + jx + 3] = xv3;
        __syncthreads();

        // ---- ha = tanh(x @ Wa1 + ba1) -> ha_t[h][s], 2 h per thread ----
        {
            const int h0 = tid;
            float a0r[16], a1r[16];
            const float b0 = ba1[h0], b1 = ba1[h0 + 256];
            #pragma unroll
            for (int s = 0; s < 16; ++s) { a0r[s] = b0; a1r[s] = b1; }
            #pragma unroll 4
            for (int jb = 0; jb < 16; ++jb) {
                float w0[4], w1[4];
                #pragma unroll
                for (int q = 0; q < 4; ++q) {
                    w0[q] = Wa1[(jb * 4 + q) * HSZ + h0];
                    w1[q] = Wa1[(jb * 4 + q) * HSZ + h0 + 256];
                }
                #pragma unroll
                for (int s = 0; s < 16; ++s) {
                    const f32x4 xr = *(const f32x4*)&x_lds[s * SSZ + jb * 4];
                    a0r[s] += xr.x*w0[0] + xr.y*w0[1] + xr.z*w0[2] + xr.w*w0[3];
                    a1r[s] += xr.x*w1[0] + xr.y*w1[1] + xr.z*w1[2] + xr.w*w1[3];
                }
            }
            #pragma unroll
            for (int s = 0; s < 16; ++s) { a0r[s] = tanhf(a0r[s]); a1r[s] = tanhf(a1r[s]); }
            #pragma unroll
            for (int q = 0; q < 4; ++q) {
                f32x4 v0, v1;
                v0.x=a0r[q*4+0]; v0.y=a0r[q*4+1]; v0.z=a0r[q*4+2]; v0.w=a0r[q*4+3];
                v1.x=a1r[q*4+0]; v1.y=a1r[q*4+1]; v1.z=a1r[q*4+2]; v1.w=a1r[q*4+3];
                *(f32x4*)&ha_t[h0 * HA_STR + q * 4] = v0;
                *(f32x4*)&ha_t[(h0 + 256) * HA_STR + q * 4] = v1;
            }
        }
        __syncthreads();   // ha_t complete (cross-wave h ownership)

        // ---- G-GEMM, h-split by wave, barrier-free pipelined chunks ----
        f32x4 acc[16];
        {
            const f32x4 zero = {0.f, 0.f, 0.f, 0.f};
            const f32x4 ini = (wv == 0) ? ba2r : zero;  // ba2 counted once
            #pragma unroll
            for (int s = 0; s < 16; ++s) acc[s] = ini;
        }
        for (int k = 0; k < NCH; ++k) {
            if (k + 2 < NCH) {
                #pragma unroll
                for (int it = 0; it < 8; ++it)
                    stage16(Wa2 + (size_t)((k + 2) * 32 + wv * 8 + it) * 4096 + c0,
                            wch + (((k + 2) % 3) * 32 + wv * 8 + it) * 256);
                asm volatile("s_waitcnt vmcnt(16)" ::: "memory");
            } else if (k + 1 < NCH) {
                asm volatile("s_waitcnt vmcnt(8)" ::: "memory");
            } else {
                asm volatile("s_waitcnt vmcnt(0)" ::: "memory");
            }
            __builtin_amdgcn_sched_barrier(0);

            const float* wb = wch + (k % 3) * 8192 + (wv * 8) * 256;
            const float* hb = ha_t + (size_t)(k * 32 + wv * 8) * HA_STR;
            #pragma unroll 2
            for (int rr = 0; rr < 8; ++rr) {
                const f32x4 w4 = *(const f32x4*)(wb + rr * 256 + lane * 4);
                const f32x4 h0 = *(const f32x4*)(hb + rr * HA_STR + 0);
                const f32x4 h1 = *(const f32x4*)(hb + rr * HA_STR + 4);
                const f32x4 h2 = *(const f32x4*)(hb + rr * HA_STR + 8);
                const f32x4 h3 = *(const f32x4*)(hb + rr * HA_STR + 12);
                acc[0]  += h0.x * w4; acc[1]  += h0.y * w4;
                acc[2]  += h0.z * w4; acc[3]  += h0.w * w4;
                acc[4]  += h1.x * w4; acc[5]  += h1.y * w4;
                acc[6]  += h1.z * w4; acc[7]  += h1.w * w4;
                acc[8]  += h2.x * w4; acc[9]  += h2.y * w4;
                acc[10] += h2.z * w4; acc[11] += h2.w * w4;
                acc[12] += h3.x * w4; acc[13] += h3.y * w4;
                acc[14] += h3.z * w4; acc[15] += h3.w * w4;
            }
        }

        // ---- contraction (linear in G => per-wave partials are fine) ----
        float part[16];
        #pragma unroll
        for (int s = 0; s < 16; ++s) {
            const f32x4 xr = *(const f32x4*)&x_lds[s * SSZ + j0];
            part[s] = acc[s].x*xr.x + acc[s].y*xr.y + acc[s].z*xr.z + acc[s].w*xr.w;
        }
        #pragma unroll
        for (int s = 0; s < 16; ++s) {
            part[s] += __shfl_xor(part[s], 1);
            part[s] += __shfl_xor(part[s], 2);
            part[s] += __shfl_xor(part[s], 4);
            part[s] += __shfl_xor(part[s], 8);
        }
        if ((lane & 15) == 0) {
            const int il = lane >> 4;
            #pragma unroll
            for (int s = 0; s < 16; ++s)
                red[(wv * 4 + il) * 16 + s] = part[s];
        }
        __syncthreads();

        // ---- wave0: cross-wave sum, += bu, publish tagged word ----
        if (wv == 0) {
            const long b = bbase + s_e;
            const int  i = ct * 4 + il_e;
            float r = red[(0 * 4 + il_e) * 16 + s_e]
                    + red[(1 * 4 + il_e) * 16 + s_e]
                    + red[(2 * 4 + il_e) * 16 + s_e]
                    + red[(3 * 4 + il_e) * 16 + s_e];
            const float xn = r + bu_v;
            out[(b * TSZ + t) * SSZ + i] = xn;           // final (write-once)
            const u64 w = ((u64)(unsigned)(t + 1) << 32)
                        | (u64)__float_as_uint(xn);
            __hip_atomic_store(xbuf + (size_t)(t & 3) * (BSZ * SSZ) + b * SSZ + i,
                               w, __ATOMIC_RELAXED, __HIP_MEMORY_SCOPE_AGENT);
        }
        // no trailing barrier needed: wch rows are wave-private; x_lds/ha_t/red
        // rewrites at t+1 are ordered by the post-exchange __syncthreads.
    }
}

// ---------------------------------------------------------------------------
extern "C" void kernel_launch(void* const* d_in, const int* in_sizes, int n_in,
                              void* d_out, int out_size, void* d_ws, size_t ws_size,
                              hipStream_t stream) {
    const float* x0  = (const float*)d_in[0];
    const float* us  = (const float*)d_in[1];
    const float* Wa1 = (const float*)d_in[2];
    const float* ba1 = (const float*)d_in[3];
    const float* Wa2 = (const float*)d_in[4];
    const float* ba2 = (const float*)d_in[5];
    const float* Wb1 = (const float*)d_in[6];
    const float* bb1 = (const float*)d_in[7];
    const float* Wb2 = (const float*)d_in[8];
    const float* bb2 = (const float*)d_in[9];
    float* out = (float*)d_out;

    u64* xbuf = (u64*)d_ws;   // [4][256][64] tagged words, 512KB

    // zero the exchange tags (captured => runs every replay; replay-safe)
    hipMemsetAsync(xbuf, 0, (size_t)4 * BSZ * SSZ * sizeof(u64), stream);

    // Phase 1: bu -> d_out (B*T/16 = 4096 WGs)
    hipLaunchKernelGGL(bu_kernel, dim3((BSZ * TSZ) / 16), dim3(256), 0, stream,
                       us, Wb1, bb1, Wb2, bb2, out);

    // Phase 2: sequential rollout (cooperative for co-residency; 141KB LDS)
    (void)hipFuncSetAttribute((const void*)ssm_kernel,
                              hipFuncAttributeMaxDynamicSharedMemorySize, SMEM_BYTES);
    void* args[] = {(void*)&x0, (void*)&Wa1, (void*)&ba1,
                    (void*)&Wa2, (void*)&ba2, (void*)&out, (void*)&xbuf};
    hipLaunchCooperativeKernel((const void*)ssm_kernel, dim3(256), dim3(256),
                               args, SMEM_BYTES, stream);
}

// Round 7
// 8240.752 us; speedup vs baseline: 6.0900x; 1.1629x over previous
//
#include <hip/hip_runtime.h>

#define BSZ 256
#define TSZ 256
#define SSZ 64
#define ASZ 16
#define HSZ 512

#define NCH 16                    // 16 chunks of 32 h-rows per step
#define HA_STR 20                 // padded [h][s] stride (floats)

#define X_OFF   0                                  // [16][64]    = 1024 floats
#define HA_OFF  1024                               // [512][20]   = 10240 floats
#define W_OFF   (HA_OFF + HSZ * HA_STR)            // [3][32][256]= 24576 floats
#define RED_OFF (W_OFF + 3 * 32 * 256)             // [8][4][16]  = 512 floats
#define SMEM_FLOATS (RED_OFF + 512)                // 36352
#define SMEM_BYTES  (SMEM_FLOATS * 4)              // 145408 B

typedef float f32x4 __attribute__((ext_vector_type(4)));
typedef unsigned long long u64;

__device__ __forceinline__ void stage16(const float* gp, float* lp) {
    // async global->LDS, 16B/lane; LDS dest = wave-uniform base + lane*16
    __builtin_amdgcn_global_load_lds(
        (const __attribute__((address_space(1))) void*)gp,
        (__attribute__((address_space(3))) void*)lp, 16, 0, 0);
}

// Tagged-word exchange: value and validity in ONE 8B atomic object.
__device__ __forceinline__ float wait_tag(const u64* p, unsigned tag) {
    u64 v = __hip_atomic_load(p, __ATOMIC_RELAXED, __HIP_MEMORY_SCOPE_AGENT);
    while ((unsigned)(v >> 32) != tag) {
        __builtin_amdgcn_s_sleep(1);
        v = __hip_atomic_load(p, __ATOMIC_RELAXED, __HIP_MEMORY_SCOPE_AGENT);
    }
    return __uint_as_float((unsigned)v);
}

// ---------------------------------------------------------------------------
// Kernel 1: bu[b,t,i] = (tanh(u@Wb1+bb1) @ Wb2 + bb2).reshape(S,A) @ u
// written directly into d_out[b,t,i]. 16 samples per WG. (unchanged)
// ---------------------------------------------------------------------------
__global__ __launch_bounds__(256) void bu_kernel(
    const float* __restrict__ us,
    const float* __restrict__ Wb1, const float* __restrict__ bb1,
    const float* __restrict__ Wb2, const float* __restrict__ bb2,
    float* __restrict__ out)
{
    __shared__ float u_lds[16][16];
    __shared__ float hb_lds[16][HSZ + 4];

    const int tid = threadIdx.x;
    const long s0 = (long)blockIdx.x * 16;

    u_lds[tid >> 4][tid & 15] = us[s0 * ASZ + tid];
    __syncthreads();

    #pragma unroll
    for (int rep = 0; rep < 2; ++rep) {
        const int h = tid + rep * 256;
        float acc[16];
        const float b1 = bb1[h];
        #pragma unroll
        for (int s = 0; s < 16; ++s) acc[s] = b1;
        #pragma unroll
        for (int a = 0; a < ASZ; ++a) {
            const float w = Wb1[a * HSZ + h];
            #pragma unroll
            for (int s = 0; s < 16; ++s) acc[s] += u_lds[s][a] * w;
        }
        #pragma unroll
        for (int s = 0; s < 16; ++s) hb_lds[s][h] = tanhf(acc[s]);
    }
    __syncthreads();

    const int i  = tid & 63;
    const int sg = tid >> 6;

    float ur[4][ASZ];
    #pragma unroll
    for (int s4 = 0; s4 < 4; ++s4)
        #pragma unroll
        for (int a = 0; a < ASZ; ++a) ur[s4][a] = u_lds[sg * 4 + s4][a];

    float acc[4];
    {
        float wb[ASZ];
        const float4* bp = (const float4*)(bb2 + i * ASZ);
        #pragma unroll
        for (int q = 0; q < 4; ++q) {
            float4 v = bp[q];
            wb[q*4+0] = v.x; wb[q*4+1] = v.y; wb[q*4+2] = v.z; wb[q*4+3] = v.w;
        }
        #pragma unroll
        for (int s4 = 0; s4 < 4; ++s4) {
            float t = 0.f;
            #pragma unroll
            for (int a = 0; a < ASZ; ++a) t += wb[a] * ur[s4][a];
            acc[s4] = t;
        }
    }

    for (int h = 0; h < HSZ; ++h) {
        float w[ASZ];
        const float4* wp = (const float4*)(Wb2 + (size_t)h * (SSZ * ASZ) + i * ASZ);
        #pragma unroll
        for (int q = 0; q < 4; ++q) {
            float4 v = wp[q];
            w[q*4+0] = v.x; w[q*4+1] = v.y; w[q*4+2] = v.z; w[q*4+3] = v.w;
        }
        #pragma unroll
        for (int s4 = 0; s4 < 4; ++s4) {
            float t = 0.f;
            #pragma unroll
            for (int a = 0; a < ASZ; ++a) t += w[a] * ur[s4][a];
            acc[s4] += hb_lds[sg * 4 + s4][h] * t;
        }
    }

    #pragma unroll
    for (int s4 = 0; s4 < 4; ++s4)
        out[(s0 + sg * 4 + s4) * SSZ + i] = acc[s4];
}

// ---------------------------------------------------------------------------
// Kernel 2: sequential rollout. 256 WGs = 16 bt-groups x 16 ct. 1 WG/CU,
// now 512 threads = 8 waves = 2 waves/SIMD (latency hiding).
// Exchange: tagged 8B atomic words (round-6 protocol, verified).
// G-GEMM: h-split by wave -> 4 rows/wave/chunk, barrier-free pipelined
// chunks, counted vmcnt ladder 8/4/0 (4 loads per wave per chunk).
// ---------------------------------------------------------------------------
__global__ __launch_bounds__(512, 1) void ssm_kernel(
    const float* __restrict__ x0,
    const float* __restrict__ Wa1, const float* __restrict__ ba1,
    const float* __restrict__ Wa2, const float* __restrict__ ba2,
    float* __restrict__ out, u64* __restrict__ xbuf)
{
    extern __shared__ float smem[];
    float* x_lds = smem + X_OFF;     // [16][64]
    float* ha_t  = smem + HA_OFF;    // [512][HA_STR]
    float* wch   = smem + W_OFF;     // [3][32][256]
    float* red   = smem + RED_OFF;   // [8 wv][4 il][16 s]

    const int tid  = threadIdx.x;
    const int lane = tid & 63;
    const int wv   = tid >> 6;       // 0..7
    const int bt = blockIdx.x >> 4;
    const int ct = blockIdx.x & 15;
    const long bbase = (long)bt * 16;

    const int c0 = ct * 256 + lane * 4;          // 4 global Wa2 cols per thread
    const f32x4 ba2r = *(const f32x4*)(ba2 + c0);
    const int j0 = (lane & 15) * 4;              // x sub-block for contraction
    const int s_e = lane & 15, il_e = lane >> 4; // wave0 epilogue mapping

    for (int t = 0; t < TSZ; ++t) {
        // ---- stage chunks 0,1 (this wave's own 4 rows of each) ----
        #pragma unroll
        for (int it = 0; it < 4; ++it)
            stage16(Wa2 + (size_t)(wv * 4 + it) * 4096 + c0,
                    wch + (0 * 32 + wv * 4 + it) * 256);
        #pragma unroll
        for (int it = 0; it < 4; ++it)
            stage16(Wa2 + (size_t)(32 + wv * 4 + it) * 4096 + c0,
                    wch + (1 * 32 + wv * 4 + it) * 256);

        // ---- bu (wave0 only; cached load of bytes only bu_kernel wrote) ----
        float bu_v = 0.f;
        if (wv == 0)
            bu_v = out[((bbase + s_e) * TSZ + t) * SSZ + (ct * 4 + il_e)];

        // ---- obtain x_{t-1} (first 4 waves; stages/bu already in flight) ----
        if (tid < 256) {
            const int sx = tid >> 4, jx = (tid & 15) * 4;
            float xv0, xv1, xv2, xv3;
            if (t > 0) {
                const u64* xs = xbuf + (size_t)((t - 1) & 3) * (BSZ * SSZ)
                              + (bbase + sx) * SSZ + jx;
                xv0 = wait_tag(xs + 0, (unsigned)t);
                xv1 = wait_tag(xs + 1, (unsigned)t);
                xv2 = wait_tag(xs + 2, (unsigned)t);
                xv3 = wait_tag(xs + 3, (unsigned)t);
            } else {
                const f32x4 x4 = *(const f32x4*)(x0 + (bbase + sx) * SSZ + jx);
                xv0 = x4.x; xv1 = x4.y; xv2 = x4.z; xv3 = x4.w;
            }
            x_lds[sx * SSZ + jx + 0] = xv0;
            x_lds[sx * SSZ + jx + 1] = xv1;
            x_lds[sx * SSZ + jx + 2] = xv2;
            x_lds[sx * SSZ + jx + 3] = xv3;
        }
        __syncthreads();

        // ---- ha = tanh(x @ Wa1 + ba1) -> ha_t[h][s], 1 h per thread ----
        {
            const int h0 = tid;
            float ar[16];
            const float b0 = ba1[h0];
            #pragma unroll
            for (int s = 0; s < 16; ++s) ar[s] = b0;
            #pragma unroll 4
            for (int jb = 0; jb < 16; ++jb) {
                float w0[4];
                #pragma unroll
                for (int q = 0; q < 4; ++q)
                    w0[q] = Wa1[(jb * 4 + q) * HSZ + h0];
                #pragma unroll
                for (int s = 0; s < 16; ++s) {
                    const f32x4 xr = *(const f32x4*)&x_lds[s * SSZ + jb * 4];
                    ar[s] += xr.x*w0[0] + xr.y*w0[1] + xr.z*w0[2] + xr.w*w0[3];
                }
            }
            #pragma unroll
            for (int s = 0; s < 16; ++s) ar[s] = tanhf(ar[s]);
            #pragma unroll
            for (int q = 0; q < 4; ++q) {
                f32x4 v0;
                v0.x=ar[q*4+0]; v0.y=ar[q*4+1]; v0.z=ar[q*4+2]; v0.w=ar[q*4+3];
                *(f32x4*)&ha_t[h0 * HA_STR + q * 4] = v0;
            }
        }
        __syncthreads();   // ha_t complete (cross-wave h ownership)

        // ---- G-GEMM, h-split by wave (4 rows/chunk), barrier-free ----
        f32x4 acc[16];
        {
            const f32x4 zero = {0.f, 0.f, 0.f, 0.f};
            const f32x4 ini = (wv == 0) ? ba2r : zero;  // ba2 counted once
            #pragma unroll
            for (int s = 0; s < 16; ++s) acc[s] = ini;
        }
        for (int k = 0; k < NCH; ++k) {
            if (k + 2 < NCH) {
                #pragma unroll
                for (int it = 0; it < 4; ++it)
                    stage16(Wa2 + (size_t)((k + 2) * 32 + wv * 4 + it) * 4096 + c0,
                            wch + (((k + 2) % 3) * 32 + wv * 4 + it) * 256);
                asm volatile("s_waitcnt vmcnt(8)" ::: "memory");  // chunk k landed
            } else if (k + 1 < NCH) {
                asm volatile("s_waitcnt vmcnt(4)" ::: "memory");
            } else {
                asm volatile("s_waitcnt vmcnt(0)" ::: "memory");
            }
            __builtin_amdgcn_sched_barrier(0);

            const float* wb = wch + (k % 3) * 8192 + (wv * 4) * 256;
            const float* hb = ha_t + (size_t)(k * 32 + wv * 4) * HA_STR;
            #pragma unroll
            for (int rr = 0; rr < 4; ++rr) {
                const f32x4 w4 = *(const f32x4*)(wb + rr * 256 + lane * 4);
                const f32x4 h0 = *(const f32x4*)(hb + rr * HA_STR + 0);
                const f32x4 h1 = *(const f32x4*)(hb + rr * HA_STR + 4);
                const f32x4 h2 = *(const f32x4*)(hb + rr * HA_STR + 8);
                const f32x4 h3 = *(const f32x4*)(hb + rr * HA_STR + 12);
                acc[0]  += h0.x * w4; acc[1]  += h0.y * w4;
                acc[2]  += h0.z * w4; acc[3]  += h0.w * w4;
                acc[4]  += h1.x * w4; acc[5]  += h1.y * w4;
                acc[6]  += h1.z * w4; acc[7]  += h1.w * w4;
                acc[8]  += h2.x * w4; acc[9]  += h2.y * w4;
                acc[10] += h2.z * w4; acc[11] += h2.w * w4;
                acc[12] += h3.x * w4; acc[13] += h3.y * w4;
                acc[14] += h3.z * w4; acc[15] += h3.w * w4;
            }
        }

        // ---- contraction (linear in G => per-wave partials are fine) ----
        float part[16];
        #pragma unroll
        for (int s = 0; s < 16; ++s) {
            const f32x4 xr = *(const f32x4*)&x_lds[s * SSZ + j0];
            part[s] = acc[s].x*xr.x + acc[s].y*xr.y + acc[s].z*xr.z + acc[s].w*xr.w;
        }
        #pragma unroll
        for (int s = 0; s < 16; ++s) {
            part[s] += __shfl_xor(part[s], 1);
            part[s] += __shfl_xor(part[s], 2);
            part[s] += __shfl_xor(part[s], 4);
            part[s] += __shfl_xor(part[s], 8);
        }
        if ((lane & 15) == 0) {
            const int il = lane >> 4;
            #pragma unroll
            for (int s = 0; s < 16; ++s)
                red[(wv * 4 + il) * 16 + s] = part[s];
        }
        __syncthreads();

        // ---- wave0: cross-wave sum, += bu, publish tagged word ----
        if (wv == 0) {
            const long b = bbase + s_e;
            const int  i = ct * 4 + il_e;
            float r = 0.f;
            #pragma unroll
            for (int w8 = 0; w8 < 8; ++w8)
                r += red[(w8 * 4 + il_e) * 16 + s_e];
            const float xn = r + bu_v;
            out[(b * TSZ + t) * SSZ + i] = xn;           // final (write-once)
            const u64 w = ((u64)(unsigned)(t + 1) << 32)
                        | (u64)__float_as_uint(xn);
            __hip_atomic_store(xbuf + (size_t)(t & 3) * (BSZ * SSZ) + b * SSZ + i,
                               w, __ATOMIC_RELAXED, __HIP_MEMORY_SCOPE_AGENT);
        }
        // wch rows are wave-private; x_lds/ha_t/red rewrites at t+1 are
        // ordered by the post-exchange __syncthreads.
    }
}

// ---------------------------------------------------------------------------
extern "C" void kernel_launch(void* const* d_in, const int* in_sizes, int n_in,
                              void* d_out, int out_size, void* d_ws, size_t ws_size,
                              hipStream_t stream) {
    const float* x0  = (const float*)d_in[0];
    const float* us  = (const float*)d_in[1];
    const float* Wa1 = (const float*)d_in[2];
    const float* ba1 = (const float*)d_in[3];
    const float* Wa2 = (const float*)d_in[4];
    const float* ba2 = (const float*)d_in[5];
    const float* Wb1 = (const float*)d_in[6];
    const float* bb1 = (const float*)d_in[7];
    const float* Wb2 = (const float*)d_in[8];
    const float* bb2 = (const float*)d_in[9];
    float* out = (float*)d_out;

    u64* xbuf = (u64*)d_ws;   // [4][256][64] tagged words, 512KB

    // zero the exchange tags (captured => runs every replay; replay-safe)
    hipMemsetAsync(xbuf, 0, (size_t)4 * BSZ * SSZ * sizeof(u64), stream);

    // Phase 1: bu -> d_out (B*T/16 = 4096 WGs)
    hipLaunchKernelGGL(bu_kernel, dim3((BSZ * TSZ) / 16), dim3(256), 0, stream,
                       us, Wb1, bb1, Wb2, bb2, out);

    // Phase 2: sequential rollout (cooperative for co-residency; 142KB LDS)
    (void)hipFuncSetAttribute((const void*)ssm_kernel,
                              hipFuncAttributeMaxDynamicSharedMemorySize, SMEM_BYTES);
    void* args[] = {(void*)&x0, (void*)&Wa1, (void*)&ba1,
                    (void*)&Wa2, (void*)&ba2, (void*)&out, (void*)&xbuf};
    hipLaunchCooperativeKernel((const void*)ssm_kernel, dim3(256), dim3(512),
                               args, SMEM_BYTES, stream);
}

// Round 9
// 8208.237 us; speedup vs baseline: 6.1141x; 1.0040x over previous
//
#include <hip/hip_runtime.h>

#define BSZ 256
#define TSZ 256
#define SSZ 64
#define ASZ 16
#define HSZ 512

typedef float f32x4 __attribute__((ext_vector_type(4)));
typedef short bf16x8 __attribute__((ext_vector_type(8)));
typedef unsigned short u16x8 __attribute__((ext_vector_type(8)));
typedef unsigned long long u64;
typedef unsigned short ushort_t;

// ---------------- workspace layout ----------------
#define XBUF_BYTES ((size_t)4 * BSZ * SSZ * sizeof(u64))              // 512KB
#define WT_ELEMS   ((size_t)4096 * 512)                               // per comp
#define WS_NEEDED  (XBUF_BYTES + 3 * WT_ELEMS * sizeof(ushort_t))     // ~12.6MB

// ---------------- MFMA ssm LDS layout (bytes) ----------------
#define MF_X_OFF    0                        // [16][64] f32 = 4096
#define MF_RED_OFF  4096                     // [8][16] f32  = 512
#define MF_HAH_OFF  4608                     // [16][520] u16 = 16640
#define MF_HAM_OFF  (4608 + 16640)           // 21248
#define MF_HAL_OFF  (21248 + 16640)          // 37888
#define MF_WCH_OFF  (37888 + 16640)          // 54528: 2 bufs x 3 comps x 16KB
#define MF_SMEM     (54528 + 2 * 3 * 16384)  // 152832 B (< 160KB)

// ---------------- f32 fallback LDS layout (round 7, verified) ----------------
#define NCH 16
#define HA_STR 20
#define X_OFF   0
#define HA_OFF  1024
#define W_OFF   (HA_OFF + HSZ * HA_STR)
#define RED_OFF (W_OFF + 3 * 32 * 256)
#define SMEM_FLOATS (RED_OFF + 512)
#define SMEM_BYTES  (SMEM_FLOATS * 4)        // 145408 B

__device__ __forceinline__ void stage16(const void* gp, void* lp) {
    // async global->LDS, 16B/lane; LDS dest = wave-uniform base + lane*16
    __builtin_amdgcn_global_load_lds(
        (const __attribute__((address_space(1))) void*)gp,
        (__attribute__((address_space(3))) void*)lp, 16, 0, 0);
}

// Tagged-word exchange: value and validity in ONE 8B atomic object. (verified r6/r7)
__device__ __forceinline__ float wait_tag(const u64* p, unsigned tag) {
    u64 v = __hip_atomic_load(p, __ATOMIC_RELAXED, __HIP_MEMORY_SCOPE_AGENT);
    while ((unsigned)(v >> 32) != tag) {
        __builtin_amdgcn_s_sleep(1);
        v = __hip_atomic_load(p, __ATOMIC_RELAXED, __HIP_MEMORY_SCOPE_AGENT);
    }
    return __uint_as_float((unsigned)v);
}

// bf16 split helpers (RNE)
__device__ __forceinline__ ushort_t f32_to_bf16(float f) {
    unsigned u = __float_as_uint(f);
    unsigned r = u + 0x7FFFu + ((u >> 16) & 1u);
    return (ushort_t)(r >> 16);
}
__device__ __forceinline__ float bf16_to_f32(ushort_t h) {
    return __uint_as_float((unsigned)h << 16);
}

// ---------------------------------------------------------------------------
// Kernel 0: transpose + 3-way bf16-split Wa2[512][4096] -> wth/wtm/wtl [4096][512]
// ---------------------------------------------------------------------------
__global__ __launch_bounds__(256) void wsplit_kernel(
    const float* __restrict__ Wa2,
    ushort_t* __restrict__ wth, ushort_t* __restrict__ wtm,
    ushort_t* __restrict__ wtl)
{
    __shared__ float tile[64][65];
    const int bc = blockIdx.x & 63;   // col tile
    const int bh = blockIdx.x >> 6;   // h tile
    const int c0 = bc * 64, h0 = bh * 64;
    const int tid = threadIdx.x;

    const int lr = tid >> 4, lc4 = (tid & 15) * 4;
    #pragma unroll
    for (int p = 0; p < 4; ++p) {
        const int h = p * 16 + lr;
        *(f32x4*)&tile[h][lc4] =
            *(const f32x4*)(Wa2 + (size_t)(h0 + h) * 4096 + c0 + lc4);
    }
    __syncthreads();

    const int col = tid >> 2, hb = (tid & 3) * 16;
    u16x8 H0, H1, M0, M1, L0, L1;
    #pragma unroll
    for (int q = 0; q < 16; ++q) {
        const float v = tile[hb + q][col];
        const ushort_t H = f32_to_bf16(v);
        const float r1 = v - bf16_to_f32(H);
        const ushort_t M = f32_to_bf16(r1);
        const ushort_t L = f32_to_bf16(r1 - bf16_to_f32(M));
        if (q < 8) { H0[q] = H; M0[q] = M; L0[q] = L; }
        else       { H1[q-8] = H; M1[q-8] = M; L1[q-8] = L; }
    }
    const size_t off = (size_t)(c0 + col) * 512 + h0 + hb;
    *(u16x8*)(wth + off) = H0;  *(u16x8*)(wth + off + 8) = H1;
    *(u16x8*)(wtm + off) = M0;  *(u16x8*)(wtm + off + 8) = M1;
    *(u16x8*)(wtl + off) = L0;  *(u16x8*)(wtl + off + 8) = L1;
}

// ---------------------------------------------------------------------------
// Kernel 1: bu[b,t,i] -> d_out[b,t,i]. 16 samples per WG. (unchanged)
// ---------------------------------------------------------------------------
__global__ __launch_bounds__(256) void bu_kernel(
    const float* __restrict__ us,
    const float* __restrict__ Wb1, const float* __restrict__ bb1,
    const float* __restrict__ Wb2, const float* __restrict__ bb2,
    float* __restrict__ out)
{
    __shared__ float u_lds[16][16];
    __shared__ float hb_lds[16][HSZ + 4];

    const int tid = threadIdx.x;
    const long s0 = (long)blockIdx.x * 16;

    u_lds[tid >> 4][tid & 15] = us[s0 * ASZ + tid];
    __syncthreads();

    #pragma unroll
    for (int rep = 0; rep < 2; ++rep) {
        const int h = tid + rep * 256;
        float acc[16];
        const float b1 = bb1[h];
        #pragma unroll
        for (int s = 0; s < 16; ++s) acc[s] = b1;
        #pragma unroll
        for (int a = 0; a < ASZ; ++a) {
            const float w = Wb1[a * HSZ + h];
            #pragma unroll
            for (int s = 0; s < 16; ++s) acc[s] += u_lds[s][a] * w;
        }
        #pragma unroll
        for (int s = 0; s < 16; ++s) hb_lds[s][h] = tanhf(acc[s]);
    }
    __syncthreads();

    const int i  = tid & 63;
    const int sg = tid >> 6;

    float ur[4][ASZ];
    #pragma unroll
    for (int s4 = 0; s4 < 4; ++s4)
        #pragma unroll
        for (int a = 0; a < ASZ; ++a) ur[s4][a] = u_lds[sg * 4 + s4][a];

    float acc[4];
    {
        float wb[ASZ];
        const float4* bp = (const float4*)(bb2 + i * ASZ);
        #pragma unroll
        for (int q = 0; q < 4; ++q) {
            float4 v = bp[q];
            wb[q*4+0] = v.x; wb[q*4+1] = v.y; wb[q*4+2] = v.z; wb[q*4+3] = v.w;
        }
        #pragma unroll
        for (int s4 = 0; s4 < 4; ++s4) {
            float t = 0.f;
            #pragma unroll
            for (int a = 0; a < ASZ; ++a) t += wb[a] * ur[s4][a];
            acc[s4] = t;
        }
    }

    for (int h = 0; h < HSZ; ++h) {
        float w[ASZ];
        const float4* wp = (const float4*)(Wb2 + (size_t)h * (SSZ * ASZ) + i * ASZ);
        #pragma unroll
        for (int q = 0; q < 4; ++q) {
            float4 v = wp[q];
            w[q*4+0] = v.x; w[q*4+1] = v.y; w[q*4+2] = v.z; w[q*4+3] = v.w;
        }
        #pragma unroll
        for (int s4 = 0; s4 < 4; ++s4) {
            float t = 0.f;
            #pragma unroll
            for (int a = 0; a < ASZ; ++a) t += w[a] * ur[s4][a];
            acc[s4] += hb_lds[sg * 4 + s4][h] * t;
        }
    }

    #pragma unroll
    for (int s4 = 0; s4 < 4; ++s4)
        out[(s0 + sg * 4 + s4) * SSZ + i] = acc[s4];
}

// ---------------------------------------------------------------------------
// Kernel 2: MFMA rollout, 3-way bf16 split, 6-pass (f32-emulation grade).
// 256 WGs = 16 bt x 16 ct, 512 thr (8 waves). Wave owns 32 G-cols, full K.
// W streamed as 3 pre-split comps via wave-private global_load_lds chunks
// (32 h each, 2 bufs depth-1, vmcnt 6/0, barrier-free). ha f32 -> 3-way
// split in LDS [s][h]. Per K-step: 3 A-frags + 6 B-frags, 12 MFMA
// (small-first). Epilogue unchanged (round-8 mapping, +ba2, x-contract,
// shfl-reduce, tagged-word exchange).
// ---------------------------------------------------------------------------
__global__ __launch_bounds__(512, 1) void ssm_mfma(
    const float* __restrict__ x0,
    const float* __restrict__ Wa1, const float* __restrict__ ba1,
    const ushort_t* __restrict__ wth, const ushort_t* __restrict__ wtm,
    const ushort_t* __restrict__ wtl, const float* __restrict__ ba2,
    float* __restrict__ out, u64* __restrict__ xbuf)
{
    extern __shared__ char smem[];
    float* x_lds = (float*)(smem + MF_X_OFF);
    float* red   = (float*)(smem + MF_RED_OFF);
    char*  haH   = smem + MF_HAH_OFF;     // [16][520] u16, row 1040B
    char*  haM   = smem + MF_HAM_OFF;
    char*  haL   = smem + MF_HAL_OFF;
    char*  wch   = smem + MF_WCH_OFF;     // 2 bufs x {H,M,L 16KB each}

    const int tid  = threadIdx.x;
    const int lane = tid & 63;
    const int wv   = tid >> 6;
    const int l15  = lane & 15, lg = lane >> 4;
    const int bt = blockIdx.x >> 4, ct = blockIdx.x & 15;
    const long bbase = (long)bt * 16;

    // staging source addressing (per-lane): col = 32wv + (lane>>2) [+16],
    // h-slot = (lane&3)*8 within the 32-h chunk
    const size_t wt_off = (size_t)(ct * 256 + 32 * wv + (lane >> 2)) * 512
                        + (lane & 3) * 8;

    const float ba2v0 = ba2[ct * 256 + 32 * wv + l15];
    const float ba2v1 = ba2[ct * 256 + 32 * wv + 16 + l15];
    const int jt  = 32 * (wv & 1) + l15;
    const int s_e = l15, q_e = lg;

    const int abyte  = l15 * 1040 + lg * 16;
    const int b0byte = (32 * wv + l15) * 64 + lg * 16;
    const int b1byte = b0byte + 1024;

    for (int t = 0; t < TSZ; ++t) {
        // ---- prestage chunk 0 -> buf 0 (lands under spin/ha) ----
        {
            char* db = wch + 0 * 49152 + (32 * wv) * 64;
            const ushort_t* gH = wth + wt_off;
            const ushort_t* gM = wtm + wt_off;
            const ushort_t* gL = wtl + wt_off;
            stage16(gH, db);             stage16(gH + 16*512, db + 1024);
            stage16(gM, db + 16384);     stage16(gM + 16*512, db + 16384 + 1024);
            stage16(gL, db + 32768);     stage16(gL + 16*512, db + 32768 + 1024);
        }

        // ---- bu (wave0; cached load of bytes only bu_kernel wrote) ----
        float bu_v = 0.f;
        if (wv == 0)
            bu_v = out[((bbase + s_e) * TSZ + t) * SSZ + (ct * 4 + q_e)];

        // ---- obtain x_{t-1} (first 4 waves) ----
        if (tid < 256) {
            const int sx = tid >> 4, jx = (tid & 15) * 4;
            float xv0, xv1, xv2, xv3;
            if (t > 0) {
                const u64* xs = xbuf + (size_t)((t - 1) & 3) * (BSZ * SSZ)
                              + (bbase + sx) * SSZ + jx;
                xv0 = wait_tag(xs + 0, (unsigned)t);
                xv1 = wait_tag(xs + 1, (unsigned)t);
                xv2 = wait_tag(xs + 2, (unsigned)t);
                xv3 = wait_tag(xs + 3, (unsigned)t);
            } else {
                const f32x4 x4 = *(const f32x4*)(x0 + (bbase + sx) * SSZ + jx);
                xv0 = x4.x; xv1 = x4.y; xv2 = x4.z; xv3 = x4.w;
            }
            x_lds[sx * SSZ + jx + 0] = xv0;
            x_lds[sx * SSZ + jx + 1] = xv1;
            x_lds[sx * SSZ + jx + 2] = xv2;
            x_lds[sx * SSZ + jx + 3] = xv3;
        }
        __syncthreads();

        // ---- ha = tanh(x @ Wa1 + ba1) -> 3-way bf16 split in LDS [s][h] ----
        {
            const int h0 = tid;
            float ar[16];
            const float b0 = ba1[h0];
            #pragma unroll
            for (int s = 0; s < 16; ++s) ar[s] = b0;
            #pragma unroll 4
            for (int jb = 0; jb < 16; ++jb) {
                float w0[4];
                #pragma unroll
                for (int q = 0; q < 4; ++q)
                    w0[q] = Wa1[(jb * 4 + q) * HSZ + h0];
                #pragma unroll
                for (int s = 0; s < 16; ++s) {
                    const f32x4 xr = *(const f32x4*)&x_lds[s * SSZ + jb * 4];
                    ar[s] += xr.x*w0[0] + xr.y*w0[1] + xr.z*w0[2] + xr.w*w0[3];
                }
            }
            #pragma unroll
            for (int s = 0; s < 16; ++s) {
                const float v = tanhf(ar[s]);
                const ushort_t H = f32_to_bf16(v);
                const float r1 = v - bf16_to_f32(H);
                const ushort_t M = f32_to_bf16(r1);
                const ushort_t L = f32_to_bf16(r1 - bf16_to_f32(M));
                ((ushort_t*)(haH + s * 1040))[h0] = H;
                ((ushort_t*)(haM + s * 1040))[h0] = M;
                ((ushort_t*)(haL + s * 1040))[h0] = L;
            }
        }
        __syncthreads();   // ha complete (cross-wave h ownership)

        // ---- MFMA G-GEMM: 16 K-chunks, 6-pass 3x3 split, barrier-free ----
        f32x4 acc0 = {0.f, 0.f, 0.f, 0.f};
        f32x4 acc1 = {0.f, 0.f, 0.f, 0.f};
        #pragma unroll
        for (int k = 0; k < 16; ++k) {
            if (k + 1 < 16) {
                char* db = wch + ((k + 1) & 1) * 49152 + (32 * wv) * 64;
                const ushort_t* gH = wth + wt_off + (k + 1) * 32;
                const ushort_t* gM = wtm + wt_off + (k + 1) * 32;
                const ushort_t* gL = wtl + wt_off + (k + 1) * 32;
                stage16(gH, db);             stage16(gH + 16*512, db + 1024);
                stage16(gM, db + 16384);     stage16(gM + 16*512, db + 16384 + 1024);
                stage16(gL, db + 32768);     stage16(gL + 16*512, db + 32768 + 1024);
                asm volatile("s_waitcnt vmcnt(6)" ::: "memory"); // chunk k landed
            } else {
                asm volatile("s_waitcnt vmcnt(0)" ::: "memory");
            }
            __builtin_amdgcn_sched_barrier(0);

            const char* wb = wch + (k & 1) * 49152;
            const bf16x8 aH  = *(const bf16x8*)(haH + k * 64 + abyte);
            const bf16x8 aM  = *(const bf16x8*)(haM + k * 64 + abyte);
            const bf16x8 aL  = *(const bf16x8*)(haL + k * 64 + abyte);
            const bf16x8 b0H = *(const bf16x8*)(wb + b0byte);
            const bf16x8 b0M = *(const bf16x8*)(wb + 16384 + b0byte);
            const bf16x8 b0L = *(const bf16x8*)(wb + 32768 + b0byte);
            const bf16x8 b1H = *(const bf16x8*)(wb + b1byte);
            const bf16x8 b1M = *(const bf16x8*)(wb + 16384 + b1byte);
            const bf16x8 b1L = *(const bf16x8*)(wb + 32768 + b1byte);

            // small-first accumulation
            acc0 = __builtin_amdgcn_mfma_f32_16x16x32_bf16(aL, b0H, acc0, 0, 0, 0);
            acc0 = __builtin_amdgcn_mfma_f32_16x16x32_bf16(aM, b0M, acc0, 0, 0, 0);
            acc0 = __builtin_amdgcn_mfma_f32_16x16x32_bf16(aH, b0L, acc0, 0, 0, 0);
            acc0 = __builtin_amdgcn_mfma_f32_16x16x32_bf16(aM, b0H, acc0, 0, 0, 0);
            acc0 = __builtin_amdgcn_mfma_f32_16x16x32_bf16(aH, b0M, acc0, 0, 0, 0);
            acc0 = __builtin_amdgcn_mfma_f32_16x16x32_bf16(aH, b0H, acc0, 0, 0, 0);
            acc1 = __builtin_amdgcn_mfma_f32_16x16x32_bf16(aL, b1H, acc1, 0, 0, 0);
            acc1 = __builtin_amdgcn_mfma_f32_16x16x32_bf16(aM, b1M, acc1, 0, 0, 0);
            acc1 = __builtin_amdgcn_mfma_f32_16x16x32_bf16(aH, b1L, acc1, 0, 0, 0);
            acc1 = __builtin_amdgcn_mfma_f32_16x16x32_bf16(aM, b1H, acc1, 0, 0, 0);
            acc1 = __builtin_amdgcn_mfma_f32_16x16x32_bf16(aH, b1M, acc1, 0, 0, 0);
            acc1 = __builtin_amdgcn_mfma_f32_16x16x32_bf16(aH, b1H, acc1, 0, 0, 0);
        }

        // ---- epilogue: +ba2, x-contract, reduce 16 lanes, publish ----
        float part[4];
        #pragma unroll
        for (int r = 0; r < 4; ++r) {
            const int s = lg * 4 + r;                    // C row (m89 layout)
            part[r] = (acc0[r] + ba2v0) * x_lds[s * SSZ + jt]
                    + (acc1[r] + ba2v1) * x_lds[s * SSZ + jt + 16];
            part[r] += __shfl_xor(part[r], 1);
            part[r] += __shfl_xor(part[r], 2);
            part[r] += __shfl_xor(part[r], 4);
            part[r] += __shfl_xor(part[r], 8);
        }
        if (l15 == 0) {
            #pragma unroll
            for (int r = 0; r < 4; ++r)
                red[wv * 16 + lg * 4 + r] = part[r];
        }
        __syncthreads();

        if (wv == 0) {
            const long b = bbase + s_e;
            const int  i = ct * 4 + q_e;
            const float xn = red[(2 * q_e) * 16 + s_e]
                           + red[(2 * q_e + 1) * 16 + s_e] + bu_v;
            out[(b * TSZ + t) * SSZ + i] = xn;           // final (write-once)
            const u64 w = ((u64)(unsigned)(t + 1) << 32)
                        | (u64)__float_as_uint(xn);
            __hip_atomic_store(xbuf + (size_t)(t & 3) * (BSZ * SSZ) + b * SSZ + i,
                               w, __ATOMIC_RELAXED, __HIP_MEMORY_SCOPE_AGENT);
        }
    }
}

// ---------------------------------------------------------------------------
// Kernel 2 (FALLBACK, round-7 f32 path, used when ws_size < WS_NEEDED)
// ---------------------------------------------------------------------------
__global__ __launch_bounds__(512, 1) void ssm_f32(
    const float* __restrict__ x0,
    const float* __restrict__ Wa1, const float* __restrict__ ba1,
    const float* __restrict__ Wa2, const float* __restrict__ ba2,
    float* __restrict__ out, u64* __restrict__ xbuf)
{
    extern __shared__ float smemf[];
    float* x_lds = smemf + X_OFF;
    float* ha_t  = smemf + HA_OFF;
    float* wchf  = smemf + W_OFF;
    float* redf  = smemf + RED_OFF;

    const int tid  = threadIdx.x;
    const int lane = tid & 63;
    const int wv   = tid >> 6;
    const int bt = blockIdx.x >> 4;
    const int ct = blockIdx.x & 15;
    const long bbase = (long)bt * 16;

    const int c0 = ct * 256 + lane * 4;
    const f32x4 ba2r = *(const f32x4*)(ba2 + c0);
    const int j0 = (lane & 15) * 4;
    const int s_e = lane & 15, il_e = lane >> 4;

    for (int t = 0; t < TSZ; ++t) {
        #pragma unroll
        for (int it = 0; it < 4; ++it)
            stage16(Wa2 + (size_t)(wv * 4 + it) * 4096 + c0,
                    wchf + (0 * 32 + wv * 4 + it) * 256);
        #pragma unroll
        for (int it = 0; it < 4; ++it)
            stage16(Wa2 + (size_t)(32 + wv * 4 + it) * 4096 + c0,
                    wchf + (1 * 32 + wv * 4 + it) * 256);

        float bu_v = 0.f;
        if (wv == 0)
            bu_v = out[((bbase + s_e) * TSZ + t) * SSZ + (ct * 4 + il_e)];

        if (tid < 256) {
            const int sx = tid >> 4, jx = (tid & 15) * 4;
            float xv0, xv1, xv2, xv3;
            if (t > 0) {
                const u64* xs = xbuf + (size_t)((t - 1) & 3) * (BSZ * SSZ)
                              + (bbase + sx) * SSZ + jx;
                xv0 = wait_tag(xs + 0, (unsigned)t);
                xv1 = wait_tag(xs + 1, (unsigned)t);
                xv2 = wait_tag(xs + 2, (unsigned)t);
                xv3 = wait_tag(xs + 3, (unsigned)t);
            } else {
                const f32x4 x4 = *(const f32x4*)(x0 + (bbase + sx) * SSZ + jx);
                xv0 = x4.x; xv1 = x4.y; xv2 = x4.z; xv3 = x4.w;
            }
            x_lds[sx * SSZ + jx + 0] = xv0;
            x_lds[sx * SSZ + jx + 1] = xv1;
            x_lds[sx * SSZ + jx + 2] = xv2;
            x_lds[sx * SSZ + jx + 3] = xv3;
        }
        __syncthreads();

        {
            const int h0 = tid;
            float ar[16];
            const float b0 = ba1[h0];
            #pragma unroll
            for (int s = 0; s < 16; ++s) ar[s] = b0;
            #pragma unroll 4
            for (int jb = 0; jb < 16; ++jb) {
                float w0[4];
                #pragma unroll
                for (int q = 0; q < 4; ++q)
                    w0[q] = Wa1[(jb * 4 + q) * HSZ + h0];
                #pragma unroll
                for (int s = 0; s < 16; ++s) {
                    const f32x4 xr = *(const f32x4*)&x_lds[s * SSZ + jb * 4];
                    ar[s] += xr.x*w0[0] + xr.y*w0[1] + xr.z*w0[2] + xr.w*w0[3];
                }
            }
            #pragma unroll
            for (int s = 0; s < 16; ++s) ar[s] = tanhf(ar[s]);
            #pragma unroll
            for (int q = 0; q < 4; ++q) {
                f32x4 v0;
                v0.x=ar[q*4+0]; v0.y=ar[q*4+1]; v0.z=ar[q*4+2]; v0.w=ar[q*4+3];
                *(f32x4*)&ha_t[h0 * HA_STR + q * 4] = v0;
            }
        }
        __syncthreads();

        f32x4 acc[16];
        {
            const f32x4 zero = {0.f, 0.f, 0.f, 0.f};
            const f32x4 ini = (wv == 0) ? ba2r : zero;
            #pragma unroll
            for (int s = 0; s < 16; ++s) acc[s] = ini;
        }
        for (int k = 0; k < NCH; ++k) {
            if (k + 2 < NCH) {
                #pragma unroll
                for (int it = 0; it < 4; ++it)
                    stage16(Wa2 + (size_t)((k + 2) * 32 + wv * 4 + it) * 4096 + c0,
                            wchf + (((k + 2) % 3) * 32 + wv * 4 + it) * 256);
                asm volatile("s_waitcnt vmcnt(8)" ::: "memory");
            } else if (k + 1 < NCH) {
                asm volatile("s_waitcnt vmcnt(4)" ::: "memory");
            } else {
                asm volatile("s_waitcnt vmcnt(0)" ::: "memory");
            }
            __builtin_amdgcn_sched_barrier(0);

            const float* wb = wchf + (k % 3) * 8192 + (wv * 4) * 256;
            const float* hb = ha_t + (size_t)(k * 32 + wv * 4) * HA_STR;
            #pragma unroll
            for (int rr = 0; rr < 4; ++rr) {
                const f32x4 w4 = *(const f32x4*)(wb + rr * 256 + lane * 4);
                const f32x4 h0 = *(const f32x4*)(hb + rr * HA_STR + 0);
                const f32x4 h1 = *(const f32x4*)(hb + rr * HA_STR + 4);
                const f32x4 h2 = *(const f32x4*)(hb + rr * HA_STR + 8);
                const f32x4 h3 = *(const f32x4*)(hb + rr * HA_STR + 12);
                acc[0]  += h0.x * w4; acc[1]  += h0.y * w4;
                acc[2]  += h0.z * w4; acc[3]  += h0.w * w4;
                acc[4]  += h1.x * w4; acc[5]  += h1.y * w4;
                acc[6]  += h1.z * w4; acc[7]  += h1.w * w4;
                acc[8]  += h2.x * w4; acc[9]  += h2.y * w4;
                acc[10] += h2.z * w4; acc[11] += h2.w * w4;
                acc[12] += h3.x * w4; acc[13] += h3.y * w4;
                acc[14] += h3.z * w4; acc[15] += h3.w * w4;
            }
        }

        float part[16];
        #pragma unroll
        for (int s = 0; s < 16; ++s) {
            const f32x4 xr = *(const f32x4*)&x_lds[s * SSZ + j0];
            part[s] = acc[s].x*xr.x + acc[s].y*xr.y + acc[s].z*xr.z + acc[s].w*xr.w;
        }
        #pragma unroll
        for (int s = 0; s < 16; ++s) {
            part[s] += __shfl_xor(part[s], 1);
            part[s] += __shfl_xor(part[s], 2);
            part[s] += __shfl_xor(part[s], 4);
            part[s] += __shfl_xor(part[s], 8);
        }
        if ((lane & 15) == 0) {
            const int il = lane >> 4;
            #pragma unroll
            for (int s = 0; s < 16; ++s)
                redf[(wv * 4 + il) * 16 + s] = part[s];
        }
        __syncthreads();

        if (wv == 0) {
            const long b = bbase + s_e;
            const int  i = ct * 4 + il_e;
            float r = 0.f;
            #pragma unroll
            for (int w8 = 0; w8 < 8; ++w8)
                r += redf[(w8 * 4 + il_e) * 16 + s_e];
            const float xn = r + bu_v;
            out[(b * TSZ + t) * SSZ + i] = xn;
            const u64 w = ((u64)(unsigned)(t + 1) << 32)
                        | (u64)__float_as_uint(xn);
            __hip_atomic_store(xbuf + (size_t)(t & 3) * (BSZ * SSZ) + b * SSZ + i,
                               w, __ATOMIC_RELAXED, __HIP_MEMORY_SCOPE_AGENT);
        }
    }
}

// ---------------------------------------------------------------------------
extern "C" void kernel_launch(void* const* d_in, const int* in_sizes, int n_in,
                              void* d_out, int out_size, void* d_ws, size_t ws_size,
                              hipStream_t stream) {
    const float* x0  = (const float*)d_in[0];
    const float* us  = (const float*)d_in[1];
    const float* Wa1 = (const float*)d_in[2];
    const float* ba1 = (const float*)d_in[3];
    const float* Wa2 = (const float*)d_in[4];
    const float* ba2 = (const float*)d_in[5];
    const float* Wb1 = (const float*)d_in[6];
    const float* bb1 = (const float*)d_in[7];
    const float* Wb2 = (const float*)d_in[8];
    const float* bb2 = (const float*)d_in[9];
    float* out = (float*)d_out;

    u64* xbuf = (u64*)d_ws;   // [4][256][64] tagged words, 512KB
    hipMemsetAsync(xbuf, 0, XBUF_BYTES, stream);

    // Phase 1: bu -> d_out
    hipLaunchKernelGGL(bu_kernel, dim3((BSZ * TSZ) / 16), dim3(256), 0, stream,
                       us, Wb1, bb1, Wb2, bb2, out);

    if (ws_size >= WS_NEEDED) {
        ushort_t* wth = (ushort_t*)((char*)d_ws + XBUF_BYTES);
        ushort_t* wtm = wth + WT_ELEMS;
        ushort_t* wtl = wtm + WT_ELEMS;
        // Phase 0: transpose + 3-way split Wa2
        hipLaunchKernelGGL(wsplit_kernel, dim3(512), dim3(256), 0, stream,
                           Wa2, wth, wtm, wtl);
        (void)hipFuncSetAttribute((const void*)ssm_mfma,
                                  hipFuncAttributeMaxDynamicSharedMemorySize, MF_SMEM);
        void* args[] = {(void*)&x0, (void*)&Wa1, (void*)&ba1,
                        (void*)&wth, (void*)&wtm, (void*)&wtl, (void*)&ba2,
                        (void*)&out, (void*)&xbuf};
        hipLaunchCooperativeKernel((const void*)ssm_mfma, dim3(256), dim3(512),
                                   args, MF_SMEM, stream);
    } else {
        (void)hipFuncSetAttribute((const void*)ssm_f32,
                                  hipFuncAttributeMaxDynamicSharedMemorySize, SMEM_BYTES);
        void* args[] = {(void*)&x0, (void*)&Wa1, (void*)&ba1,
                        (void*)&Wa2, (void*)&ba2, (void*)&out, (void*)&xbuf};
        hipLaunchCooperativeKernel((const void*)ssm_f32, dim3(256), dim3(512),
                                   args, SMEM_BYTES, stream);
    }
}

// Round 10
// 7172.009 us; speedup vs baseline: 6.9975x; 1.1445x over previous
//
#include <hip/hip_runtime.h>

#define BSZ 256
#define TSZ 256
#define SSZ 64
#define ASZ 16
#define HSZ 512

typedef float f32x4 __attribute__((ext_vector_type(4)));
typedef short bf16x8 __attribute__((ext_vector_type(8)));
typedef unsigned short u16x8 __attribute__((ext_vector_type(8)));
typedef unsigned long long u64;
typedef unsigned short ushort_t;

// ---------------- workspace layout ----------------
#define XBUF_BYTES ((size_t)4 * BSZ * SSZ * sizeof(u64))              // 512KB
#define WT_ELEMS   ((size_t)4096 * 512)                               // per comp
#define WS_NEEDED  (XBUF_BYTES + 3 * WT_ELEMS * sizeof(ushort_t))     // ~12.6MB

// Tiled W layout (per comp), designed so global_load_lds's linear LDS write
// yields a conflict-free [slot][col] fragment order:
//   elem index = ((tile32col*16 + k) * 4 + slot) * 32 + col) * 8 + e
//   tile32col = global_col >> 5 (0..127), k = h >> 5 (0..15),
//   slot = (h >> 3) & 3, col = global_col & 31, e = h & 7.
// One (tile,k) tile = 1024 elems = 2KB contiguous.

// ---------------- MFMA ssm LDS layout (bytes) ----------------
#define MF_X_OFF    0                        // [16][64] f32 = 4096
#define MF_RED_OFF  4096                     // [8][16] f32  = 512
#define MF_HAH_OFF  4608                     // [16][520] u16 = 16640
#define MF_HAM_OFF  (4608 + 16640)           // 21248
#define MF_HAL_OFF  (21248 + 16640)          // 37888
#define MF_WCH_OFF  (37888 + 16640)          // 54528: 2 bufs x 3 comps x 16KB
#define MF_SMEM     (54528 + 2 * 3 * 16384)  // 152832 B (< 160KB)

// ---------------- f32 fallback LDS layout (round 7, verified) ----------------
#define NCH 16
#define HA_STR 20
#define X_OFF   0
#define HA_OFF  1024
#define W_OFF   (HA_OFF + HSZ * HA_STR)
#define RED_OFF (W_OFF + 3 * 32 * 256)
#define SMEM_FLOATS (RED_OFF + 512)
#define SMEM_BYTES  (SMEM_FLOATS * 4)        // 145408 B

__device__ __forceinline__ void stage16(const void* gp, void* lp) {
    // async global->LDS, 16B/lane; LDS dest = wave-uniform base + lane*16
    __builtin_amdgcn_global_load_lds(
        (const __attribute__((address_space(1))) void*)gp,
        (__attribute__((address_space(3))) void*)lp, 16, 0, 0);
}

// Tagged-word exchange: value and validity in ONE 8B atomic object. (verified r6/r7)
__device__ __forceinline__ float wait_tag(const u64* p, unsigned tag) {
    u64 v = __hip_atomic_load(p, __ATOMIC_RELAXED, __HIP_MEMORY_SCOPE_AGENT);
    while ((unsigned)(v >> 32) != tag) {
        __builtin_amdgcn_s_sleep(1);
        v = __hip_atomic_load(p, __ATOMIC_RELAXED, __HIP_MEMORY_SCOPE_AGENT);
    }
    return __uint_as_float((unsigned)v);
}

// bf16 split helpers (RNE)
__device__ __forceinline__ ushort_t f32_to_bf16(float f) {
    unsigned u = __float_as_uint(f);
    unsigned r = u + 0x7FFFu + ((u >> 16) & 1u);
    return (ushort_t)(r >> 16);
}
__device__ __forceinline__ float bf16_to_f32(ushort_t h) {
    return __uint_as_float((unsigned)h << 16);
}

// ---------------------------------------------------------------------------
// Kernel 0: transpose + 3-way bf16-split Wa2[512][4096] -> tiled wth/wtm/wtl
// ---------------------------------------------------------------------------
__global__ __launch_bounds__(256) void wsplit_kernel(
    const float* __restrict__ Wa2,
    ushort_t* __restrict__ wth, ushort_t* __restrict__ wtm,
    ushort_t* __restrict__ wtl)
{
    __shared__ float tile[64][65];
    const int bc = blockIdx.x & 63;   // col tile
    const int bh = blockIdx.x >> 6;   // h tile
    const int c0 = bc * 64, h0 = bh * 64;
    const int tid = threadIdx.x;

    const int lr = tid >> 4, lc4 = (tid & 15) * 4;
    #pragma unroll
    for (int p = 0; p < 4; ++p) {
        const int h = p * 16 + lr;
        *(f32x4*)&tile[h][lc4] =
            *(const f32x4*)(Wa2 + (size_t)(h0 + h) * 4096 + c0 + lc4);
    }
    __syncthreads();

    const int col = tid >> 2, hb = (tid & 3) * 16;
    u16x8 H0, H1, M0, M1, L0, L1;
    #pragma unroll
    for (int q = 0; q < 16; ++q) {
        const float v = tile[hb + q][col];
        const ushort_t H = f32_to_bf16(v);
        const float r1 = v - bf16_to_f32(H);
        const ushort_t M = f32_to_bf16(r1);
        const ushort_t L = f32_to_bf16(r1 - bf16_to_f32(M));
        if (q < 8) { H0[q] = H; M0[q] = M; L0[q] = L; }
        else       { H1[q-8] = H; M1[q-8] = M; L1[q-8] = L; }
    }
    // tiled destination (see layout comment above)
    const int col_g = c0 + col;
    const int hbase = h0 + hb;                 // multiple of 16
    const int kk    = hbase >> 5;
    const int sl0   = (hbase >> 3) & 3;        // slot of first 8 h
    const size_t atom0 = (((size_t)(col_g >> 5) * 16 + kk) * 4 + sl0) * 32
                       + (col_g & 31);
    const size_t atom1 = atom0 + 32;           // slot+1, same tile/k
    *(u16x8*)(wth + atom0 * 8) = H0;  *(u16x8*)(wth + atom1 * 8) = H1;
    *(u16x8*)(wtm + atom0 * 8) = M0;  *(u16x8*)(wtm + atom1 * 8) = M1;
    *(u16x8*)(wtl + atom0 * 8) = L0;  *(u16x8*)(wtl + atom1 * 8) = L1;
}

// ---------------------------------------------------------------------------
// Kernel 1: bu[b,t,i] -> d_out[b,t,i]. 16 samples per WG. (unchanged)
// ---------------------------------------------------------------------------
__global__ __launch_bounds__(256) void bu_kernel(
    const float* __restrict__ us,
    const float* __restrict__ Wb1, const float* __restrict__ bb1,
    const float* __restrict__ Wb2, const float* __restrict__ bb2,
    float* __restrict__ out)
{
    __shared__ float u_lds[16][16];
    __shared__ float hb_lds[16][HSZ + 4];

    const int tid = threadIdx.x;
    const long s0 = (long)blockIdx.x * 16;

    u_lds[tid >> 4][tid & 15] = us[s0 * ASZ + tid];
    __syncthreads();

    #pragma unroll
    for (int rep = 0; rep < 2; ++rep) {
        const int h = tid + rep * 256;
        float acc[16];
        const float b1 = bb1[h];
        #pragma unroll
        for (int s = 0; s < 16; ++s) acc[s] = b1;
        #pragma unroll
        for (int a = 0; a < ASZ; ++a) {
            const float w = Wb1[a * HSZ + h];
            #pragma unroll
            for (int s = 0; s < 16; ++s) acc[s] += u_lds[s][a] * w;
        }
        #pragma unroll
        for (int s = 0; s < 16; ++s) hb_lds[s][h] = tanhf(acc[s]);
    }
    __syncthreads();

    const int i  = tid & 63;
    const int sg = tid >> 6;

    float ur[4][ASZ];
    #pragma unroll
    for (int s4 = 0; s4 < 4; ++s4)
        #pragma unroll
        for (int a = 0; a < ASZ; ++a) ur[s4][a] = u_lds[sg * 4 + s4][a];

    float acc[4];
    {
        float wb[ASZ];
        const float4* bp = (const float4*)(bb2 + i * ASZ);
        #pragma unroll
        for (int q = 0; q < 4; ++q) {
            float4 v = bp[q];
            wb[q*4+0] = v.x; wb[q*4+1] = v.y; wb[q*4+2] = v.z; wb[q*4+3] = v.w;
        }
        #pragma unroll
        for (int s4 = 0; s4 < 4; ++s4) {
            float t = 0.f;
            #pragma unroll
            for (int a = 0; a < ASZ; ++a) t += wb[a] * ur[s4][a];
            acc[s4] = t;
        }
    }

    for (int h = 0; h < HSZ; ++h) {
        float w[ASZ];
        const float4* wp = (const float4*)(Wb2 + (size_t)h * (SSZ * ASZ) + i * ASZ);
        #pragma unroll
        for (int q = 0; q < 4; ++q) {
            float4 v = wp[q];
            w[q*4+0] = v.x; w[q*4+1] = v.y; w[q*4+2] = v.z; w[q*4+3] = v.w;
        }
        #pragma unroll
        for (int s4 = 0; s4 < 4; ++s4) {
            float t = 0.f;
            #pragma unroll
            for (int a = 0; a < ASZ; ++a) t += w[a] * ur[s4][a];
            acc[s4] += hb_lds[sg * 4 + s4][h] * t;
        }
    }

    #pragma unroll
    for (int s4 = 0; s4 < 4; ++s4)
        out[(s0 + sg * 4 + s4) * SSZ + i] = acc[s4];
}

// ---------------------------------------------------------------------------
// Kernel 2: MFMA rollout, 3-way bf16 split, 6-pass. 256 WGs, 512 thr (8 wv).
// W streamed from the TILED workspace: per comp per chunk, 2 contiguous 1KB
// global_load_lds per wave -> LDS [slot][col] order -> B-frag ds_read_b128
// is 4 contiguous 256B quarter-wave reads = bank-conflict-free.
// Fragment (col,k)->lane mapping identical to round 9 (numerics unchanged).
// ---------------------------------------------------------------------------
__global__ __launch_bounds__(512, 1) void ssm_mfma(
    const float* __restrict__ x0,
    const float* __restrict__ Wa1, const float* __restrict__ ba1,
    const ushort_t* __restrict__ wth, const ushort_t* __restrict__ wtm,
    const ushort_t* __restrict__ wtl, const float* __restrict__ ba2,
    float* __restrict__ out, u64* __restrict__ xbuf)
{
    extern __shared__ char smem[];
    float* x_lds = (float*)(smem + MF_X_OFF);
    float* red   = (float*)(smem + MF_RED_OFF);
    char*  haH   = smem + MF_HAH_OFF;     // [16][520] u16, row 1040B
    char*  haM   = smem + MF_HAM_OFF;
    char*  haL   = smem + MF_HAL_OFF;
    char*  wch   = smem + MF_WCH_OFF;     // 2 bufs x {H,M,L 16KB each}

    const int tid  = threadIdx.x;
    const int lane = tid & 63;
    const int wv   = tid >> 6;
    const int l15  = lane & 15, lg = lane >> 4;
    const int bt = blockIdx.x >> 4, ct = blockIdx.x & 15;
    const long bbase = (long)bt * 16;

    // tiled-W source: this wave's 32-col block = tile (ct*8 + wv);
    // chunk k tile base (elems) = ((ct*8+wv)*16 + k) * 1024; per-lane +lane*8.
    const size_t wtile = (size_t)((ct * 8 + wv) * 16) * 1024 + (size_t)lane * 8;

    const float ba2v0 = ba2[ct * 256 + 32 * wv + l15];
    const float ba2v1 = ba2[ct * 256 + 32 * wv + 16 + l15];
    const int jt  = 32 * (wv & 1) + l15;
    const int s_e = l15, q_e = lg;

    const int abyte  = l15 * 1040 + lg * 16;
    // conflict-free [slot][col] read: quarter-wave contiguous 256B
    const int b0byte = wv * 2048 + lg * 512 + l15 * 16;
    const int b1byte = b0byte + 256;

    for (int t = 0; t < TSZ; ++t) {
        // ---- prestage chunk 0 -> buf 0 (lands under spin/ha) ----
        {
            char* db = wch + wv * 2048;
            const ushort_t* gH = wth + wtile;
            const ushort_t* gM = wtm + wtile;
            const ushort_t* gL = wtl + wtile;
            stage16(gH, db);           stage16(gH + 512, db + 1024);
            stage16(gM, db + 16384);   stage16(gM + 512, db + 16384 + 1024);
            stage16(gL, db + 32768);   stage16(gL + 512, db + 32768 + 1024);
        }

        // ---- bu (wave0; cached load of bytes only bu_kernel wrote) ----
        float bu_v = 0.f;
        if (wv == 0)
            bu_v = out[((bbase + s_e) * TSZ + t) * SSZ + (ct * 4 + q_e)];

        // ---- obtain x_{t-1} (first 4 waves) ----
        if (tid < 256) {
            const int sx = tid >> 4, jx = (tid & 15) * 4;
            float xv0, xv1, xv2, xv3;
            if (t > 0) {
                const u64* xs = xbuf + (size_t)((t - 1) & 3) * (BSZ * SSZ)
                              + (bbase + sx) * SSZ + jx;
                xv0 = wait_tag(xs + 0, (unsigned)t);
                xv1 = wait_tag(xs + 1, (unsigned)t);
                xv2 = wait_tag(xs + 2, (unsigned)t);
                xv3 = wait_tag(xs + 3, (unsigned)t);
            } else {
                const f32x4 x4 = *(const f32x4*)(x0 + (bbase + sx) * SSZ + jx);
                xv0 = x4.x; xv1 = x4.y; xv2 = x4.z; xv3 = x4.w;
            }
            x_lds[sx * SSZ + jx + 0] = xv0;
            x_lds[sx * SSZ + jx + 1] = xv1;
            x_lds[sx * SSZ + jx + 2] = xv2;
            x_lds[sx * SSZ + jx + 3] = xv3;
        }
        __syncthreads();

        // ---- ha = tanh(x @ Wa1 + ba1) -> 3-way bf16 split in LDS [s][h] ----
        {
            const int h0 = tid;
            float ar[16];
            const float b0 = ba1[h0];
            #pragma unroll
            for (int s = 0; s < 16; ++s) ar[s] = b0;
            #pragma unroll 4
            for (int jb = 0; jb < 16; ++jb) {
                float w0[4];
                #pragma unroll
                for (int q = 0; q < 4; ++q)
                    w0[q] = Wa1[(jb * 4 + q) * HSZ + h0];
                #pragma unroll
                for (int s = 0; s < 16; ++s) {
                    const f32x4 xr = *(const f32x4*)&x_lds[s * SSZ + jb * 4];
                    ar[s] += xr.x*w0[0] + xr.y*w0[1] + xr.z*w0[2] + xr.w*w0[3];
                }
            }
            #pragma unroll
            for (int s = 0; s < 16; ++s) {
                const float v = tanhf(ar[s]);
                const ushort_t H = f32_to_bf16(v);
                const float r1 = v - bf16_to_f32(H);
                const ushort_t M = f32_to_bf16(r1);
                const ushort_t L = f32_to_bf16(r1 - bf16_to_f32(M));
                ((ushort_t*)(haH + s * 1040))[h0] = H;
                ((ushort_t*)(haM + s * 1040))[h0] = M;
                ((ushort_t*)(haL + s * 1040))[h0] = L;
            }
        }
        __syncthreads();   // ha complete (cross-wave h ownership)

        // ---- MFMA G-GEMM: 16 K-chunks, 6-pass 3x3 split, barrier-free ----
        f32x4 acc0 = {0.f, 0.f, 0.f, 0.f};
        f32x4 acc1 = {0.f, 0.f, 0.f, 0.f};
        #pragma unroll
        for (int k = 0; k < 16; ++k) {
            if (k + 1 < 16) {
                char* db = wch + ((k + 1) & 1) * 49152 + wv * 2048;
                const ushort_t* gH = wth + wtile + (size_t)(k + 1) * 1024;
                const ushort_t* gM = wtm + wtile + (size_t)(k + 1) * 1024;
                const ushort_t* gL = wtl + wtile + (size_t)(k + 1) * 1024;
                stage16(gH, db);           stage16(gH + 512, db + 1024);
                stage16(gM, db + 16384);   stage16(gM + 512, db + 16384 + 1024);
                stage16(gL, db + 32768);   stage16(gL + 512, db + 32768 + 1024);
                asm volatile("s_waitcnt vmcnt(6)" ::: "memory"); // chunk k landed
            } else {
                asm volatile("s_waitcnt vmcnt(0)" ::: "memory");
            }
            __builtin_amdgcn_sched_barrier(0);

            const char* wb = wch + (k & 1) * 49152;
            const bf16x8 aH  = *(const bf16x8*)(haH + k * 64 + abyte);
            const bf16x8 aM  = *(const bf16x8*)(haM + k * 64 + abyte);
            const bf16x8 aL  = *(const bf16x8*)(haL + k * 64 + abyte);
            const bf16x8 b0H = *(const bf16x8*)(wb + b0byte);
            const bf16x8 b0M = *(const bf16x8*)(wb + 16384 + b0byte);
            const bf16x8 b0L = *(const bf16x8*)(wb + 32768 + b0byte);
            const bf16x8 b1H = *(const bf16x8*)(wb + b1byte);
            const bf16x8 b1M = *(const bf16x8*)(wb + 16384 + b1byte);
            const bf16x8 b1L = *(const bf16x8*)(wb + 32768 + b1byte);

            // small-first accumulation
            acc0 = __builtin_amdgcn_mfma_f32_16x16x32_bf16(aL, b0H, acc0, 0, 0, 0);
            acc0 = __builtin_amdgcn_mfma_f32_16x16x32_bf16(aM, b0M, acc0, 0, 0, 0);
            acc0 = __builtin_amdgcn_mfma_f32_16x16x32_bf16(aH, b0L, acc0, 0, 0, 0);
            acc0 = __builtin_amdgcn_mfma_f32_16x16x32_bf16(aM, b0H, acc0, 0, 0, 0);
            acc0 = __builtin_amdgcn_mfma_f32_16x16x32_bf16(aH, b0M, acc0, 0, 0, 0);
            acc0 = __builtin_amdgcn_mfma_f32_16x16x32_bf16(aH, b0H, acc0, 0, 0, 0);
            acc1 = __builtin_amdgcn_mfma_f32_16x16x32_bf16(aL, b1H, acc1, 0, 0, 0);
            acc1 = __builtin_amdgcn_mfma_f32_16x16x32_bf16(aM, b1M, acc1, 0, 0, 0);
            acc1 = __builtin_amdgcn_mfma_f32_16x16x32_bf16(aH, b1L, acc1, 0, 0, 0);
            acc1 = __builtin_amdgcn_mfma_f32_16x16x32_bf16(aM, b1H, acc1, 0, 0, 0);
            acc1 = __builtin_amdgcn_mfma_f32_16x16x32_bf16(aH, b1M, acc1, 0, 0, 0);
            acc1 = __builtin_amdgcn_mfma_f32_16x16x32_bf16(aH, b1H, acc1, 0, 0, 0);
        }

        // ---- epilogue: +ba2, x-contract, reduce 16 lanes, publish ----
        float part[4];
        #pragma unroll
        for (int r = 0; r < 4; ++r) {
            const int s = lg * 4 + r;                    // C row (m89 layout)
            part[r] = (acc0[r] + ba2v0) * x_lds[s * SSZ + jt]
                    + (acc1[r] + ba2v1) * x_lds[s * SSZ + jt + 16];
            part[r] += __shfl_xor(part[r], 1);
            part[r] += __shfl_xor(part[r], 2);
            part[r] += __shfl_xor(part[r], 4);
            part[r] += __shfl_xor(part[r], 8);
        }
        if (l15 == 0) {
            #pragma unroll
            for (int r = 0; r < 4; ++r)
                red[wv * 16 + lg * 4 + r] = part[r];
        }
        __syncthreads();

        if (wv == 0) {
            const long b = bbase + s_e;
            const int  i = ct * 4 + q_e;
            const float xn = red[(2 * q_e) * 16 + s_e]
                           + red[(2 * q_e + 1) * 16 + s_e] + bu_v;
            out[(b * TSZ + t) * SSZ + i] = xn;           // final (write-once)
            const u64 w = ((u64)(unsigned)(t + 1) << 32)
                        | (u64)__float_as_uint(xn);
            __hip_atomic_store(xbuf + (size_t)(t & 3) * (BSZ * SSZ) + b * SSZ + i,
                               w, __ATOMIC_RELAXED, __HIP_MEMORY_SCOPE_AGENT);
        }
    }
}

// ---------------------------------------------------------------------------
// Kernel 2 (FALLBACK, round-7 f32 path, used when ws_size < WS_NEEDED)
// ---------------------------------------------------------------------------
__global__ __launch_bounds__(512, 1) void ssm_f32(
    const float* __restrict__ x0,
    const float* __restrict__ Wa1, const float* __restrict__ ba1,
    const float* __restrict__ Wa2, const float* __restrict__ ba2,
    float* __restrict__ out, u64* __restrict__ xbuf)
{
    extern __shared__ float smemf[];
    float* x_lds = smemf + X_OFF;
    float* ha_t  = smemf + HA_OFF;
    float* wchf  = smemf + W_OFF;
    float* redf  = smemf + RED_OFF;

    const int tid  = threadIdx.x;
    const int lane = tid & 63;
    const int wv   = tid >> 6;
    const int bt = blockIdx.x >> 4;
    const int ct = blockIdx.x & 15;
    const long bbase = (long)bt * 16;

    const int c0 = ct * 256 + lane * 4;
    const f32x4 ba2r = *(const f32x4*)(ba2 + c0);
    const int j0 = (lane & 15) * 4;
    const int s_e = lane & 15, il_e = lane >> 4;

    for (int t = 0; t < TSZ; ++t) {
        #pragma unroll
        for (int it = 0; it < 4; ++it)
            stage16(Wa2 + (size_t)(wv * 4 + it) * 4096 + c0,
                    wchf + (0 * 32 + wv * 4 + it) * 256);
        #pragma unroll
        for (int it = 0; it < 4; ++it)
            stage16(Wa2 + (size_t)(32 + wv * 4 + it) * 4096 + c0,
                    wchf + (1 * 32 + wv * 4 + it) * 256);

        float bu_v = 0.f;
        if (wv == 0)
            bu_v = out[((bbase + s_e) * TSZ + t) * SSZ + (ct * 4 + il_e)];

        if (tid < 256) {
            const int sx = tid >> 4, jx = (tid & 15) * 4;
            float xv0, xv1, xv2, xv3;
            if (t > 0) {
                const u64* xs = xbuf + (size_t)((t - 1) & 3) * (BSZ * SSZ)
                              + (bbase + sx) * SSZ + jx;
                xv0 = wait_tag(xs + 0, (unsigned)t);
                xv1 = wait_tag(xs + 1, (unsigned)t);
                xv2 = wait_tag(xs + 2, (unsigned)t);
                xv3 = wait_tag(xs + 3, (unsigned)t);
            } else {
                const f32x4 x4 = *(const f32x4*)(x0 + (bbase + sx) * SSZ + jx);
                xv0 = x4.x; xv1 = x4.y; xv2 = x4.z; xv3 = x4.w;
            }
            x_lds[sx * SSZ + jx + 0] = xv0;
            x_lds[sx * SSZ + jx + 1] = xv1;
            x_lds[sx * SSZ + jx + 2] = xv2;
            x_lds[sx * SSZ + jx + 3] = xv3;
        }
        __syncthreads();

        {
            const int h0 = tid;
            float ar[16];
            const float b0 = ba1[h0];
            #pragma unroll
            for (int s = 0; s < 16; ++s) ar[s] = b0;
            #pragma unroll 4
            for (int jb = 0; jb < 16; ++jb) {
                float w0[4];
                #pragma unroll
                for (int q = 0; q < 4; ++q)
                    w0[q] = Wa1[(jb * 4 + q) * HSZ + h0];
                #pragma unroll
                for (int s = 0; s < 16; ++s) {
                    const f32x4 xr = *(const f32x4*)&x_lds[s * SSZ + jb * 4];
                    ar[s] += xr.x*w0[0] + xr.y*w0[1] + xr.z*w0[2] + xr.w*w0[3];
                }
            }
            #pragma unroll
            for (int s = 0; s < 16; ++s) ar[s] = tanhf(ar[s]);
            #pragma unroll
            for (int q = 0; q < 4; ++q) {
                f32x4 v0;
                v0.x=ar[q*4+0]; v0.y=ar[q*4+1]; v0.z=ar[q*4+2]; v0.w=ar[q*4+3];
                *(f32x4*)&ha_t[h0 * HA_STR + q * 4] = v0;
            }
        }
        __syncthreads();

        f32x4 acc[16];
        {
            const f32x4 zero = {0.f, 0.f, 0.f, 0.f};
            const f32x4 ini = (wv == 0) ? ba2r : zero;
            #pragma unroll
            for (int s = 0; s < 16; ++s) acc[s] = ini;
        }
        for (int k = 0; k < NCH; ++k) {
            if (k + 2 < NCH) {
                #pragma unroll
                for (int it = 0; it < 4; ++it)
                    stage16(Wa2 + (size_t)((k + 2) * 32 + wv * 4 + it) * 4096 + c0,
                            wchf + (((k + 2) % 3) * 32 + wv * 4 + it) * 256);
                asm volatile("s_waitcnt vmcnt(8)" ::: "memory");
            } else if (k + 1 < NCH) {
                asm volatile("s_waitcnt vmcnt(4)" ::: "memory");
            } else {
                asm volatile("s_waitcnt vmcnt(0)" ::: "memory");
            }
            __builtin_amdgcn_sched_barrier(0);

            const float* wb = wchf + (k % 3) * 8192 + (wv * 4) * 256;
            const float* hb = ha_t + (size_t)(k * 32 + wv * 4) * HA_STR;
            #pragma unroll
            for (int rr = 0; rr < 4; ++rr) {
                const f32x4 w4 = *(const f32x4*)(wb + rr * 256 + lane * 4);
                const f32x4 h0 = *(const f32x4*)(hb + rr * HA_STR + 0);
                const f32x4 h1 = *(const f32x4*)(hb + rr * HA_STR + 4);
                const f32x4 h2 = *(const f32x4*)(hb + rr * HA_STR + 8);
                const f32x4 h3 = *(const f32x4*)(hb + rr * HA_STR + 12);
                acc[0]  += h0.x * w4; acc[1]  += h0.y * w4;
                acc[2]  += h0.z * w4; acc[3]  += h0.w * w4;
                acc[4]  += h1.x * w4; acc[5]  += h1.y * w4;
                acc[6]  += h1.z * w4; acc[7]  += h1.w * w4;
                acc[8]  += h2.x * w4; acc[9]  += h2.y * w4;
                acc[10] += h2.z * w4; acc[11] += h2.w * w4;
                acc[12] += h3.x * w4; acc[13] += h3.y * w4;
                acc[14] += h3.z * w4; acc[15] += h3.w * w4;
            }
        }

        float part[16];
        #pragma unroll
        for (int s = 0; s < 16; ++s) {
            const f32x4 xr = *(const f32x4*)&x_lds[s * SSZ + j0];
            part[s] = acc[s].x*xr.x + acc[s].y*xr.y + acc[s].z*xr.z + acc[s].w*xr.w;
        }
        #pragma unroll
        for (int s = 0; s < 16; ++s) {
            part[s] += __shfl_xor(part[s], 1);
            part[s] += __shfl_xor(part[s], 2);
            part[s] += __shfl_xor(part[s], 4);
            part[s] += __shfl_xor(part[s], 8);
        }
        if ((lane & 15) == 0) {
            const int il = lane >> 4;
            #pragma unroll
            for (int s = 0; s < 16; ++s)
                redf[(wv * 4 + il) * 16 + s] = part[s];
        }
        __syncthreads();

        if (wv == 0) {
            const long b = bbase + s_e;
            const int  i = ct * 4 + il_e;
            float r = 0.f;
            #pragma unroll
            for (int w8 = 0; w8 < 8; ++w8)
                r += redf[(w8 * 4 + il_e) * 16 + s_e];
            const float xn = r + bu_v;
            out[(b * TSZ + t) * SSZ + i] = xn;
            const u64 w = ((u64)(unsigned)(t + 1) << 32)
                        | (u64)__float_as_uint(xn);
            __hip_atomic_store(xbuf + (size_t)(t & 3) * (BSZ * SSZ) + b * SSZ + i,
                               w, __ATOMIC_RELAXED, __HIP_MEMORY_SCOPE_AGENT);
        }
    }
}

// ---------------------------------------------------------------------------
extern "C" void kernel_launch(void* const* d_in, const int* in_sizes, int n_in,
                              void* d_out, int out_size, void* d_ws, size_t ws_size,
                              hipStream_t stream) {
    const float* x0  = (const float*)d_in[0];
    const float* us  = (const float*)d_in[1];
    const float* Wa1 = (const float*)d_in[2];
    const float* ba1 = (const float*)d_in[3];
    const float* Wa2 = (const float*)d_in[4];
    const float* ba2 = (const float*)d_in[5];
    const float* Wb1 = (const float*)d_in[6];
    const float* bb1 = (const float*)d_in[7];
    const float* Wb2 = (const float*)d_in[8];
    const float* bb2 = (const float*)d_in[9];
    float* out = (float*)d_out;

    u64* xbuf = (u64*)d_ws;   // [4][256][64] tagged words, 512KB
    hipMemsetAsync(xbuf, 0, XBUF_BYTES, stream);

    // Phase 1: bu -> d_out
    hipLaunchKernelGGL(bu_kernel, dim3((BSZ * TSZ) / 16), dim3(256), 0, stream,
                       us, Wb1, bb1, Wb2, bb2, out);

    if (ws_size >= WS_NEEDED) {
        ushort_t* wth = (ushort_t*)((char*)d_ws + XBUF_BYTES);
        ushort_t* wtm = wth + WT_ELEMS;
        ushort_t* wtl = wtm + WT_ELEMS;
        // Phase 0: transpose + 3-way split Wa2 into tiled layout
        hipLaunchKernelGGL(wsplit_kernel, dim3(512), dim3(256), 0, stream,
                           Wa2, wth, wtm, wtl);
        (void)hipFuncSetAttribute((const void*)ssm_mfma,
                                  hipFuncAttributeMaxDynamicSharedMemorySize, MF_SMEM);
        void* args[] = {(void*)&x0, (void*)&Wa1, (void*)&ba1,
                        (void*)&wth, (void*)&wtm, (void*)&wtl, (void*)&ba2,
                        (void*)&out, (void*)&xbuf};
        hipLaunchCooperativeKernel((const void*)ssm_mfma, dim3(256), dim3(512),
                                   args, MF_SMEM, stream);
    } else {
        (void)hipFuncSetAttribute((const void*)ssm_f32,
                                  hipFuncAttributeMaxDynamicSharedMemorySize, SMEM_BYTES);
        void* args[] = {(void*)&x0, (void*)&Wa1, (void*)&ba1,
                        (void*)&Wa2, (void*)&ba2, (void*)&out, (void*)&xbuf};
        hipLaunchCooperativeKernel((const void*)ssm_f32, dim3(256), dim3(512),
                                   args, SMEM_BYTES, stream);
    }
}